// Round 6
// baseline (2524.088 us; speedup 1.0000x reference)
//
#include <hip/hip_runtime.h>
#include <cstdint>
#include <cstddef>

#define T_ 512
#define B_ 128
#define D_ 256
#define H_ 512
#define C_ 10

typedef float  f32x4 __attribute__((ext_vector_type(4)));
typedef short  s16x8 __attribute__((ext_vector_type(8)));
typedef _Float16 v8h __attribute__((ext_vector_type(8)));
typedef _Float16 v2h __attribute__((ext_vector_type(2)));

static __device__ __forceinline__ unsigned short f2bf(float f) {
    unsigned u = __builtin_bit_cast(unsigned, f);
    unsigned r = u + 0x7FFFu + ((u >> 16) & 1u);   // round-to-nearest-even
    return (unsigned short)(r >> 16);
}

// ---------------------------------------------------------------------------
// k-permutation shared by A-storage, B-fragments, h-writes:
//   col (global k) = 128*(s>>2) + 16*j + 4*kb + (s&3)
//   i.e. s = 4*(col>>7) + (col&3), kb = (col&15)>>2, j = (col>>4)&7
// Storage byte within h-buffer: 1024*s + 256*kb + 16*(row ^ kb) + 2*j
// (row^kb spreads banks for both the fragment read and the packed write)
// ---------------------------------------------------------------------------

// ---------------------------------------------------------------------------
// Prep 0: W_hx [256,512] f32 -> W_hx^T [512,256] bf16 (B-operand for k_gemm1)
// ---------------------------------------------------------------------------
__global__ void k_whxT(const float* __restrict__ Whx, unsigned short* __restrict__ WhxT) {
    int idx = blockIdx.x * 256 + threadIdx.x;
    int n = idx >> 8;
    int k = idx & 255;
    WhxT[n * 256 + k] = f2bf(Whx[k * 512 + n]);
}

// ---------------------------------------------------------------------------
// Prep 1: W_hh [512,512] f32 -> Wf: f16 MFMA B-fragments with permuted k.
// Wf entry gid = ((w*16 + s)*8 + nb)*64 + l holds 8 f16, element j:
//   B[kGlob = 128*(s>>2) + 16*j + 4*(l>>4) + (s&3)][col = 128w + 16nb + (l&15)]
// ---------------------------------------------------------------------------
__global__ void k_wfrag(const float* __restrict__ Whh, _Float16* __restrict__ Wf) {
    int gid = blockIdx.x * 256 + threadIdx.x;   // 32768 total
    int l   = gid & 63;
    int grp = gid >> 6;                          // ((w*16+s)*8+nb)
    int nb  = grp & 7;
    int s   = (grp >> 3) & 15;
    int w   = grp >> 7;
    int col = w * 128 + nb * 16 + (l & 15);
    int kb  = l >> 4;
    v8h v;
#pragma unroll
    for (int j = 0; j < 8; ++j) {
        int kGlob = 128 * (s >> 2) + 16 * j + 4 * kb + (s & 3);
        v[j] = (_Float16)Whh[(size_t)kGlob * 512 + col];
    }
    *(v8h*)(Wf + (size_t)gid * 8) = v;
}

// ---------------------------------------------------------------------------
// Phase 1: Z = x @ W_hx + b_h, written in k_rnn's Zr layout:
// Zr block (t, cu, w) = 4096 B at ((t*8+cu)*4+w)*4096, layout [g 0..3][m 0..63][q 0..7] f16,
// value(q) = z[t][16cu + (m>>4)*4 + (q&3)][128w + 16*(2g + (q>>2)) + (m&15)].
// ---------------------------------------------------------------------------
__global__ void __launch_bounds__(256) k_gemm1(const float* __restrict__ x,
                                               const unsigned short* __restrict__ WhxT,
                                               const float* __restrict__ bh,
                                               char* __restrict__ Zr) {
    __shared__ char smem[32768];
    unsigned short* Asm = (unsigned short*)smem;          // [128][32] bf16 (8 KiB)
    unsigned short* Bsm = (unsigned short*)(smem + 8192); // [128][32] bf16 (8 KiB)

    const int tid = threadIdx.x;
    const int bid = blockIdx.x;
    const int nt = bid & 3, mt = bid >> 2;
    const int r0 = mt * 128, n0 = nt * 128;
    const int w  = tid >> 6, l = tid & 63;
    const int wm = (w >> 1) * 64, wn = (w & 1) * 64;
    const int lr = l & 15, lk = (l >> 4) * 8;

    const int arow = tid >> 2, akc = (tid & 3) * 8;
    const int bcol = tid >> 1, bkc = (tid & 1) * 16;

    f32x4 acc[4][4] = {};

    for (int kk = 0; kk < 256; kk += 32) {
#pragma unroll
        for (int half = 0; half < 2; ++half) {
            const int r = arow + half * 64;
            const float* ap = x + (size_t)(r0 + r) * 256 + kk + akc;
            float4 f0 = *(const float4*)ap;
            float4 f1 = *(const float4*)(ap + 4);
            uint4 av;
            av.x = (unsigned)f2bf(f0.x) | ((unsigned)f2bf(f0.y) << 16);
            av.y = (unsigned)f2bf(f0.z) | ((unsigned)f2bf(f0.w) << 16);
            av.z = (unsigned)f2bf(f1.x) | ((unsigned)f2bf(f1.y) << 16);
            av.w = (unsigned)f2bf(f1.z) | ((unsigned)f2bf(f1.w) << 16);
            *(uint4*)&Asm[r * 32 + akc] = av;
        }
        const unsigned short* bsrc = WhxT + (size_t)(n0 + bcol) * 256 + kk + bkc;
        uint4 bv0 = *(const uint4*)bsrc;
        uint4 bv1 = *(const uint4*)(bsrc + 8);
        *(uint4*)&Bsm[bcol * 32 + bkc] = bv0;
        *(uint4*)&Bsm[bcol * 32 + bkc + 8] = bv1;
        __syncthreads();

        s16x8 af[4], bf[4];
#pragma unroll
        for (int mi = 0; mi < 4; ++mi)
            af[mi] = *(const s16x8*)&Asm[(wm + mi * 16 + lr) * 32 + lk];
#pragma unroll
        for (int ni = 0; ni < 4; ++ni)
            bf[ni] = *(const s16x8*)&Bsm[(wn + ni * 16 + lr) * 32 + lk];
#pragma unroll
        for (int mi = 0; mi < 4; ++mi)
#pragma unroll
            for (int ni = 0; ni < 4; ++ni)
                acc[mi][ni] = __builtin_amdgcn_mfma_f32_16x16x32_bf16(af[mi], bf[ni], acc[mi][ni], 0, 0, 0);
        __syncthreads();
    }

    // ---- epilogue: stage (z + bh) as f16 into Szr, then coalesced write ----
    _Float16* Szr = (_Float16*)smem;   // [cu 0..7][g 0..3][m 0..63][q 0..7] = 32 KiB
#pragma unroll
    for (int mi = 0; mi < 4; ++mi)
#pragma unroll
        for (int ni = 0; ni < 4; ++ni) {
            const int col_l = wn + ni * 16 + lr;          // 0..127
            const float bhv = bh[n0 + col_l];
            const int g   = (col_l >> 5) & 3;
            const int qhi = ((col_l >> 4) & 1) * 4;
#pragma unroll
            for (int e = 0; e < 4; ++e) {
                const int b   = wm + mi * 16 + (l >> 4) * 4 + e;   // 0..127
                const int cu  = b >> 4;
                const int m_r = ((b & 15) >> 2) * 16 + lr;
                Szr[((cu * 4 + g) * 64 + m_r) * 8 + qhi + e] = (_Float16)(acc[mi][ni][e] + bhv);
            }
        }
    __syncthreads();
    {
        const uint4* srcv = (const uint4*)smem;
#pragma unroll
        for (int i = 0; i < 8; ++i) {
            const int o   = tid * 128 + i * 16;   // byte offset in Szr
            const int cuo = o >> 12;
            char* dst = Zr + ((size_t)((mt * 8 + cuo) * 4 + nt)) * 4096 + (o & 4095);
            *(uint4*)dst = srcv[o >> 4];
        }
    }
}

// ---------------------------------------------------------------------------
// Phase 2: MFMA recurrence. 8 WGs x 256 threads (4 waves, 1/SIMD).
// WG cu owns batches [16cu,16cu+16); wave w owns cols [128w,128w+128).
// B slices 0..9 stationary in regs/AGPRs; slices 10..15 streamed from L2
// every step (Wf is L2-resident; each WG ~alone on its XCD).
// h double-buffered in LDS (2 x 16 KiB) in permuted A-fragment layout:
// reads = 16 ds_read_b128 (conflict-spread), writes = 4 ds_write_b128 packed.
// ONE barrier per step.
// ---------------------------------------------------------------------------
__global__ void __launch_bounds__(256, 1) k_rnn(const _Float16* __restrict__ Wf,
                                                const char* __restrict__ Zr,
                                                float* __restrict__ hf) {
    __shared__ _Float16 hA[2][8192];   // 32 KiB total

    const int tid = threadIdx.x;
    const int cu  = blockIdx.x;
    const int w   = tid >> 6;
    const int l   = tid & 63;
    const int r   = l & 15, q = l >> 4;

    const _Float16* WfW = Wf + (size_t)w * (16 * 8 * 64 * 8);   // this wave's 64 KiB

    // ---- stationary B slices 0..9 (320 regs, AGPR-eligible) ----
    v8h Br[10][8];
#pragma unroll
    for (int s = 0; s < 10; ++s)
#pragma unroll
        for (int nb = 0; nb < 8; ++nb)
            Br[s][nb] = *(const v8h*)(WfW + (size_t)((s * 8 + nb) * 64 + l) * 8);

    // per-thread invariant LDS offsets (bytes)
    const int roff = 256 * q + 16 * (r ^ q);
    int woff[4];
#pragma unroll
    for (int e = 0; e < 4; ++e)
        woff[e] = 1024 * (4 * w + (r & 3)) + 256 * (r >> 2) + 16 * ((4 * q + e) ^ (r >> 2));

    // h0 = 0
#pragma unroll
    for (int i = 0; i < 4; ++i)
        ((uint4*)&hA[0][0])[i * 256 + tid] = uint4{0, 0, 0, 0};
    __syncthreads();

    const char* hbase = (const char*)&hA[0][0];
    int cur = 0;

    for (int t = 0; t < T_; ++t) {
        const char* hb = hbase + cur * 16384;

        // z for this step (L3-resident, used ~1 us later)
        const v8h* zb = (const v8h*)(Zr + (((size_t)t * 8 + cu) * 4 + w) * 4096);
        v8h z8[4];
#pragma unroll
        for (int g = 0; g < 4; ++g) z8[g] = zb[g * 64 + l];

        // issue streamed slice-sets 10,11 early
        v8h Bg0[8], Bg1[8];
#pragma unroll
        for (int nb = 0; nb < 8; ++nb)
            Bg0[nb] = *(const v8h*)(WfW + (size_t)((10 * 8 + nb) * 64 + l) * 8);
#pragma unroll
        for (int nb = 0; nb < 8; ++nb)
            Bg1[nb] = *(const v8h*)(WfW + (size_t)((11 * 8 + nb) * 64 + l) * 8);

        f32x4 C[8];
        {
            v8h A = *(const v8h*)(hb + roff);                       // slice 0
#pragma unroll
            for (int nb = 0; nb < 8; ++nb)
                C[nb] = __builtin_amdgcn_mfma_f32_16x16x32_f16(A, Br[0][nb], f32x4{0.f, 0.f, 0.f, 0.f}, 0, 0, 0);
        }
#pragma unroll
        for (int s = 1; s < 10; ++s) {
            v8h A = *(const v8h*)(hb + s * 1024 + roff);
#pragma unroll
            for (int nb = 0; nb < 8; ++nb)
                C[nb] = __builtin_amdgcn_mfma_f32_16x16x32_f16(A, Br[s][nb], C[nb], 0, 0, 0);
        }
        {   // slice 10 (Bg0), refill Bg0 <- slice 12
            v8h A = *(const v8h*)(hb + 10 * 1024 + roff);
#pragma unroll
            for (int nb = 0; nb < 8; ++nb)
                C[nb] = __builtin_amdgcn_mfma_f32_16x16x32_f16(A, Bg0[nb], C[nb], 0, 0, 0);
#pragma unroll
            for (int nb = 0; nb < 8; ++nb)
                Bg0[nb] = *(const v8h*)(WfW + (size_t)((12 * 8 + nb) * 64 + l) * 8);
        }
        {   // slice 11 (Bg1), refill Bg1 <- slice 13
            v8h A = *(const v8h*)(hb + 11 * 1024 + roff);
#pragma unroll
            for (int nb = 0; nb < 8; ++nb)
                C[nb] = __builtin_amdgcn_mfma_f32_16x16x32_f16(A, Bg1[nb], C[nb], 0, 0, 0);
#pragma unroll
            for (int nb = 0; nb < 8; ++nb)
                Bg1[nb] = *(const v8h*)(WfW + (size_t)((13 * 8 + nb) * 64 + l) * 8);
        }
        {   // slice 12 (Bg0), refill Bg0 <- slice 14
            v8h A = *(const v8h*)(hb + 12 * 1024 + roff);
#pragma unroll
            for (int nb = 0; nb < 8; ++nb)
                C[nb] = __builtin_amdgcn_mfma_f32_16x16x32_f16(A, Bg0[nb], C[nb], 0, 0, 0);
#pragma unroll
            for (int nb = 0; nb < 8; ++nb)
                Bg0[nb] = *(const v8h*)(WfW + (size_t)((14 * 8 + nb) * 64 + l) * 8);
        }
        {   // slice 13 (Bg1), refill Bg1 <- slice 15
            v8h A = *(const v8h*)(hb + 13 * 1024 + roff);
#pragma unroll
            for (int nb = 0; nb < 8; ++nb)
                C[nb] = __builtin_amdgcn_mfma_f32_16x16x32_f16(A, Bg1[nb], C[nb], 0, 0, 0);
#pragma unroll
            for (int nb = 0; nb < 8; ++nb)
                Bg1[nb] = *(const v8h*)(WfW + (size_t)((15 * 8 + nb) * 64 + l) * 8);
        }
        {   // slice 14 (Bg0)
            v8h A = *(const v8h*)(hb + 14 * 1024 + roff);
#pragma unroll
            for (int nb = 0; nb < 8; ++nb)
                C[nb] = __builtin_amdgcn_mfma_f32_16x16x32_f16(A, Bg0[nb], C[nb], 0, 0, 0);
        }
        {   // slice 15 (Bg1)
            v8h A = *(const v8h*)(hb + 15 * 1024 + roff);
#pragma unroll
            for (int nb = 0; nb < 8; ++nb)
                C[nb] = __builtin_amdgcn_mfma_f32_16x16x32_f16(A, Bg1[nb], C[nb], 0, 0, 0);
        }

        // ---- epilogue: z + tanh -> 4 packed b128 writes into other h buffer ----
        char* ho = (char*)hbase + (cur ^ 1) * 16384;
#pragma unroll
        for (int e = 0; e < 4; ++e) {
            v8h hv8;
#pragma unroll
            for (int nb = 0; nb < 8; ++nb) {
                const float zf = (float)z8[nb >> 1][4 * (nb & 1) + e];
                const float sv = C[nb][e] + zf;
                const float ex = __expf(2.0f * sv);
                hv8[nb] = (_Float16)(1.0f - 2.0f * __builtin_amdgcn_rcpf(ex + 1.0f));
            }
            *(v8h*)(ho + woff[e]) = hv8;
            if (t == T_ - 1) {
#pragma unroll
                for (int nb = 0; nb < 8; ++nb)
                    hf[(size_t)(16 * cu + 4 * q + e) * 512 + 128 * w + 16 * nb + r] = (float)hv8[nb];
            }
        }
        __syncthreads();
        cur ^= 1;
    }
}

// ---------------------------------------------------------------------------
// Phase 3: out = h_final @ W_ph + b_p   [128,512]@[512,10]
// ---------------------------------------------------------------------------
__global__ void k_out(const float* __restrict__ hf, const float* __restrict__ Wph,
                      const float* __restrict__ bp, float* __restrict__ out) {
    __shared__ float red[160];
    int b = blockIdx.x, t = threadIdx.x;
    if (t < 160) {
        int c = t >> 4, ks = (t & 15) * 32;
        float s = 0.f;
        for (int u = 0; u < 32; ++u)
            s += hf[b * H_ + ks + u] * Wph[(ks + u) * C_ + c];
        red[t] = s;
    }
    __syncthreads();
    if (t < C_) {
        float s = bp[t];
        for (int i = 0; i < 16; ++i) s += red[t * 16 + i];
        out[b * C_ + t] = s;
    }
}

// ---------------------------------------------------------------------------
extern "C" void kernel_launch(void* const* d_in, const int* in_sizes, int n_in,
                              void* d_out, int out_size, void* d_ws, size_t ws_size,
                              hipStream_t stream) {
    const float* x   = (const float*)d_in[0];   // [512,128,256]
    const float* Whx = (const float*)d_in[1];   // [256,512]
    const float* Whh = (const float*)d_in[2];   // [512,512]
    const float* Wph = (const float*)d_in[3];   // [512,10]
    const float* bh  = (const float*)d_in[4];   // [512]
    const float* bp  = (const float*)d_in[5];   // [10]
    float* out = (float*)d_out;                 // [128,10] f32

    char* ws = (char*)d_ws;
    unsigned short* WhxT = (unsigned short*)(ws);                    // 256 KiB
    _Float16*       Wf   = (_Float16*)(ws + 262144);                 // 512 KiB
    char*           Zr   = ws + 786432;                              // 64 MiB
    float*          hf   = (float*)(ws + 786432 + 67108864);         // 256 KiB

    hipLaunchKernelGGL(k_whxT,  dim3(512),  dim3(256), 0, stream, Whx, WhxT);
    hipLaunchKernelGGL(k_wfrag, dim3(128),  dim3(256), 0, stream, Whh, Wf);
    hipLaunchKernelGGL(k_gemm1, dim3(2048), dim3(256), 0, stream, x, WhxT, bh, Zr);
    hipLaunchKernelGGL(k_rnn,   dim3(8),    dim3(256), 0, stream, Wf, Zr, hf);
    hipLaunchKernelGGL(k_out,   dim3(128),  dim3(256), 0, stream, hf, Wph, bp, out);
}

// Round 7
// 1117.115 us; speedup vs baseline: 2.2595x; 2.2595x over previous
//
#include <hip/hip_runtime.h>
#include <cstdint>
#include <cstddef>

#define T_ 512
#define B_ 128
#define D_ 256
#define H_ 512
#define C_ 10

// weight-pair split: 64 q-groups of 4 pairs.
// groups [0,45) = 180 pairs in VGPRs (1 packed reg each);
// groups [45,64) = 76 pairs in LDS (19 uint4/thread = 155648 B).
#define NQ_REG 45
#define NQ_LDS 19

typedef float  f32x4 __attribute__((ext_vector_type(4)));
typedef short  s16x8 __attribute__((ext_vector_type(8)));
typedef _Float16 v2h __attribute__((ext_vector_type(2)));

static __device__ __forceinline__ unsigned short f2bf(float f) {
    unsigned u = __builtin_bit_cast(unsigned, f);
    unsigned r = u + 0x7FFFu + ((u >> 16) & 1u);   // round-to-nearest-even
    return (unsigned short)(r >> 16);
}

static __device__ __forceinline__ float dot2f(v2h a, v2h b, float c) {
#if __has_builtin(__builtin_amdgcn_fdot2)
    return __builtin_amdgcn_fdot2(a, b, c, false);
#else
    return c + (float)a.x * (float)b.x + (float)a.y * (float)b.y;
#endif
}

static __device__ __forceinline__ v2h rl(unsigned v, int lane) {
    return __builtin_bit_cast(v2h, (unsigned)__builtin_amdgcn_readlane(v, lane));
}
static __device__ __forceinline__ v2h bc(unsigned v) {
    return __builtin_bit_cast(v2h, v);
}

// ---------------------------------------------------------------------------
// Prep 0: W_hx [256,512] f32 -> W_hx^T [512,256] bf16
// ---------------------------------------------------------------------------
__global__ void k_whxT(const float* __restrict__ Whx, unsigned short* __restrict__ WhxT) {
    int idx = blockIdx.x * 256 + threadIdx.x;
    int n = idx >> 8;
    int k = idx & 255;
    WhxT[n * 256 + k] = f2bf(Whx[k * 512 + n]);
}

// ---------------------------------------------------------------------------
// Prep 1: W_hh [512,512] f32 -> WpkT [512 cols][256 pairs] u32 (col-major)
//         WpkT[j*256 + r] = pack_f16(W[2r][j], W[2r+1][j])
// ---------------------------------------------------------------------------
__global__ void k_wpkT(const float* __restrict__ Whh, unsigned* __restrict__ WpkT) {
    int idx = blockIdx.x * 256 + threadIdx.x;     // 131072 total
    int j = idx >> 8;                             // 0..511 column
    int r = idx & 255;                            // 0..255 pair
    _Float16 lo = (_Float16)Whh[(2 * r) * 512 + j];
    _Float16 hi = (_Float16)Whh[(2 * r + 1) * 512 + j];
    WpkT[j * 256 + r] = (unsigned)__builtin_bit_cast(unsigned short, lo) |
                        ((unsigned)__builtin_bit_cast(unsigned short, hi) << 16);
}

// ---------------------------------------------------------------------------
// Phase 1: Z = x @ W_hx + b_h  ->  f16 Zh [T*B, H]
// ---------------------------------------------------------------------------
__global__ void __launch_bounds__(256) k_gemm1(const float* __restrict__ x,
                                               const unsigned short* __restrict__ WhxT,
                                               const float* __restrict__ bh,
                                               _Float16* __restrict__ Zh) {
    __shared__ unsigned short Asm[128 * 32];
    __shared__ unsigned short Bsm[128 * 32];
    const int tid = threadIdx.x;
    const int bid = blockIdx.x;
    const int nt = bid & 3, mt = bid >> 2;
    const int r0 = mt * 128, n0 = nt * 128;
    const int w  = tid >> 6, l = tid & 63;
    const int wm = (w >> 1) * 64, wn = (w & 1) * 64;
    const int lr = l & 15, lk = (l >> 4) * 8;

    const int arow = tid >> 2, akc = (tid & 3) * 8;
    const int bcol = tid >> 1, bkc = (tid & 1) * 16;

    f32x4 acc[4][4] = {};

    for (int kk = 0; kk < 256; kk += 32) {
#pragma unroll
        for (int half = 0; half < 2; ++half) {
            const int r = arow + half * 64;
            const float* ap = x + (size_t)(r0 + r) * 256 + kk + akc;
            float4 f0 = *(const float4*)ap;
            float4 f1 = *(const float4*)(ap + 4);
            uint4 av;
            av.x = (unsigned)f2bf(f0.x) | ((unsigned)f2bf(f0.y) << 16);
            av.y = (unsigned)f2bf(f0.z) | ((unsigned)f2bf(f0.w) << 16);
            av.z = (unsigned)f2bf(f1.x) | ((unsigned)f2bf(f1.y) << 16);
            av.w = (unsigned)f2bf(f1.z) | ((unsigned)f2bf(f1.w) << 16);
            *(uint4*)&Asm[r * 32 + akc] = av;
        }
        const unsigned short* bsrc = WhxT + (size_t)(n0 + bcol) * 256 + kk + bkc;
        uint4 bv0 = *(const uint4*)bsrc;
        uint4 bv1 = *(const uint4*)(bsrc + 8);
        *(uint4*)&Bsm[bcol * 32 + bkc] = bv0;
        *(uint4*)&Bsm[bcol * 32 + bkc + 8] = bv1;
        __syncthreads();

        s16x8 af[4], bf[4];
#pragma unroll
        for (int mi = 0; mi < 4; ++mi)
            af[mi] = *(const s16x8*)&Asm[(wm + mi * 16 + lr) * 32 + lk];
#pragma unroll
        for (int ni = 0; ni < 4; ++ni)
            bf[ni] = *(const s16x8*)&Bsm[(wn + ni * 16 + lr) * 32 + lk];
#pragma unroll
        for (int mi = 0; mi < 4; ++mi)
#pragma unroll
            for (int ni = 0; ni < 4; ++ni)
                acc[mi][ni] = __builtin_amdgcn_mfma_f32_16x16x32_bf16(af[mi], bf[ni], acc[mi][ni], 0, 0, 0);
        __syncthreads();
    }

#pragma unroll
    for (int mi = 0; mi < 4; ++mi)
#pragma unroll
        for (int ni = 0; ni < 4; ++ni) {
            int col = n0 + wn + ni * 16 + lr;
            float bhv = bh[col];
#pragma unroll
            for (int e = 0; e < 4; ++e) {
                int row = r0 + wm + mi * 16 + (l >> 4) * 4 + e;
                Zh[(size_t)row * 512 + col] = (_Float16)(acc[mi][ni][e] + bhv);
            }
        }
}

// ---------------------------------------------------------------------------
// Phase 2: recurrence. 128 WGs x 512 threads (thread = hidden column j).
// 180 weight pairs in VGPRs + 76 pairs in LDS, interleaved 2:1 with 1-deep
// LDS prefetch. h double-buffered packed-f16 in LDS; ONE ds_read_b128 per
// wave per step pulls all 256 pairs; per-pair broadcast via v_readlane ->
// SGPR operand of v_dot2_f32_f16. One barrier per step.
// amdgpu_waves_per_eu(2,2): pool 512 regs/SIMD / 2 waves = 256 VGPR cap --
// the direct knob round 3/4's __launch_bounds__ failed to turn (stuck at 128
// VGPRs -> ~90 weight pairs spilled to scratch = the 1 us/step tax).
// ---------------------------------------------------------------------------
__global__
__attribute__((amdgpu_flat_work_group_size(512, 512), amdgpu_waves_per_eu(2, 2)))
void k_rnn(const unsigned* __restrict__ WpkT,
           const _Float16* __restrict__ Zh,
           float* __restrict__ hf) {
    __shared__ uint4    Wl4[NQ_LDS * 512];   // 155648 B: weight groups [45,64)
    __shared__ unsigned hbuf[2][256];        // 2048 B: h packed f16, dbuf

    const int j = threadIdx.x;     // hidden column
    const int b = blockIdx.x;      // batch row
    const int l = j & 63;          // lane in wave

    const unsigned* wcol = WpkT + (size_t)j * 256;

    // ---- stationary weights: groups [0,45) -> 180 pairs in VGPRs ----
    v2h wreg[NQ_REG * 4];
#pragma unroll
    for (int g = 0; g < NQ_REG; ++g) {
        uint4 w = *(const uint4*)(wcol + g * 4);
        wreg[g * 4 + 0] = bc(w.x);
        wreg[g * 4 + 1] = bc(w.y);
        wreg[g * 4 + 2] = bc(w.z);
        wreg[g * 4 + 3] = bc(w.w);
    }
    // ---- groups [45,64) -> LDS ----
#pragma unroll
    for (int rb = 0; rb < NQ_LDS; ++rb)
        Wl4[rb * 512 + j] = *(const uint4*)(wcol + NQ_REG * 4 + rb * 4);

    ((_Float16*)hbuf[0])[j] = (_Float16)0.0f;   // h0 = 0
    __syncthreads();

    const _Float16* zrow = Zh + (size_t)b * H_ + j;   // T-step stride = B_*H_
    float zc = (float)zrow[0];
    float hv = 0.0f;
    int cur = 0;

    for (int t = 0; t < T_; ++t) {
        int tn = (t + 1 < T_) ? t + 1 : t;
        float zn = (float)zrow[(size_t)tn * (B_ * H_)];   // prefetch next z

        // one LDS read per wave: lane l gets h-pairs 4l..4l+3
        uint4 hv4 = ((const uint4*)hbuf[cur])[l];

        float a0 = 0.f, a1 = 0.f, a2 = 0.f, a3 = 0.f;
        uint4 w4 = Wl4[j];                                // prefetch LDS group 0
#pragma unroll
        for (int i = 0; i < NQ_LDS; ++i) {
            uint4 w4n;
            if (i + 1 < NQ_LDS) w4n = Wl4[(i + 1) * 512 + j];
            // two register groups: q = 2i, 2i+1  (covers q in [0,38))
#pragma unroll
            for (int k = 0; k < 2; ++k) {
                const int q = i * 2 + k;
                a0 = dot2f(wreg[q * 4 + 0], rl(hv4.x, q), a0);
                a1 = dot2f(wreg[q * 4 + 1], rl(hv4.y, q), a1);
                a2 = dot2f(wreg[q * 4 + 2], rl(hv4.z, q), a2);
                a3 = dot2f(wreg[q * 4 + 3], rl(hv4.w, q), a3);
            }
            // one LDS group: qL = 45 + i
            const int qL = NQ_REG + i;
            a0 = dot2f(bc(w4.x), rl(hv4.x, qL), a0);
            a1 = dot2f(bc(w4.y), rl(hv4.y, qL), a1);
            a2 = dot2f(bc(w4.z), rl(hv4.z, qL), a2);
            a3 = dot2f(bc(w4.w), rl(hv4.w, qL), a3);
            w4 = w4n;
        }
        // tail register groups: q = 38..44
#pragma unroll
        for (int q = 2 * NQ_LDS; q < NQ_REG; ++q) {
            a0 = dot2f(wreg[q * 4 + 0], rl(hv4.x, q), a0);
            a1 = dot2f(wreg[q * 4 + 1], rl(hv4.y, q), a1);
            a2 = dot2f(wreg[q * 4 + 2], rl(hv4.z, q), a2);
            a3 = dot2f(wreg[q * 4 + 3], rl(hv4.w, q), a3);
        }

        float s = (a0 + a1) + (a2 + a3) + zc;
        float e = __expf(2.0f * s);                       // tanh via exp
        hv = 1.0f - 2.0f * __builtin_amdgcn_rcpf(e + 1.0f);

        ((_Float16*)hbuf[cur ^ 1])[j] = (_Float16)hv;     // write new h to other buf
        __syncthreads();
        cur ^= 1;
        zc = zn;
    }
    hf[b * H_ + j] = hv;
}

// ---------------------------------------------------------------------------
// Phase 3: out = h_final @ W_ph + b_p   [128,512]@[512,10]
// ---------------------------------------------------------------------------
__global__ void k_out(const float* __restrict__ hf, const float* __restrict__ Wph,
                      const float* __restrict__ bp, float* __restrict__ out) {
    __shared__ float red[160];
    int b = blockIdx.x, t = threadIdx.x;
    if (t < 160) {
        int c = t >> 4, ks = (t & 15) * 32;
        float s = 0.f;
        for (int u = 0; u < 32; ++u)
            s += hf[b * H_ + ks + u] * Wph[(ks + u) * C_ + c];
        red[t] = s;
    }
    __syncthreads();
    if (t < C_) {
        float s = bp[t];
        for (int i = 0; i < 16; ++i) s += red[t * 16 + i];
        out[b * C_ + t] = s;
    }
}

// ---------------------------------------------------------------------------
extern "C" void kernel_launch(void* const* d_in, const int* in_sizes, int n_in,
                              void* d_out, int out_size, void* d_ws, size_t ws_size,
                              hipStream_t stream) {
    const float* x   = (const float*)d_in[0];   // [512,128,256]
    const float* Whx = (const float*)d_in[1];   // [256,512]
    const float* Whh = (const float*)d_in[2];   // [512,512]
    const float* Wph = (const float*)d_in[3];   // [512,10]
    const float* bh  = (const float*)d_in[4];   // [512]
    const float* bp  = (const float*)d_in[5];   // [10]
    float* out = (float*)d_out;                 // [128,10] f32

    char* ws = (char*)d_ws;
    unsigned short* WhxT = (unsigned short*)(ws);                    // 256 KiB
    unsigned*       WpkT = (unsigned*)(ws + 262144);                 // 512 KiB
    _Float16*       Zh   = (_Float16*)(ws + 786432);                 // 64 MiB
    float*          hf   = (float*)(ws + 786432 + 67108864);         // 256 KiB

    hipLaunchKernelGGL(k_whxT,  dim3(512),  dim3(256), 0, stream, Whx, WhxT);
    hipLaunchKernelGGL(k_wpkT,  dim3(512),  dim3(256), 0, stream, Whh, WpkT);
    hipLaunchKernelGGL(k_gemm1, dim3(2048), dim3(256), 0, stream, x, WhxT, bh, Zh);
    hipLaunchKernelGGL(k_rnn,   dim3(128),  dim3(512), 0, stream, WpkT, Zh, hf);
    hipLaunchKernelGGL(k_out,   dim3(128),  dim3(256), 0, stream, hf, Wph, bp, out);
}

// Round 9
// 1011.928 us; speedup vs baseline: 2.4943x; 1.1039x over previous
//
#include <hip/hip_runtime.h>
#include <cstdint>
#include <cstddef>

#define T_ 512
#define B_ 128
#define D_ 256
#define H_ 512
#define C_ 10

typedef float  f32x4 __attribute__((ext_vector_type(4)));
typedef short  s16x8 __attribute__((ext_vector_type(8)));
typedef _Float16 v8h  __attribute__((ext_vector_type(8)));
typedef unsigned u32x2 __attribute__((ext_vector_type(2)));

static __device__ __forceinline__ unsigned short f2bf(float f) {
    unsigned u = __builtin_bit_cast(unsigned, f);
    unsigned r = u + 0x7FFFu + ((u >> 16) & 1u);
    return (unsigned short)(r >> 16);
}

// ---- fp8 e4m3fn encode (HW cvt if available, else software RNE) ----
static __device__ __forceinline__ unsigned char f2e4m3_sw(float f) {
    unsigned u = __builtin_bit_cast(unsigned, f);
    unsigned sgn = (u >> 24) & 0x80u;
    float a = fabsf(f);
    if (a != a) return (unsigned char)(sgn | 0x7E);          // NaN -> max (avoid fp8 NaN)
    if (a >= 448.0f) return (unsigned char)(sgn | 0x7E);     // clamp to 448
    if (a < 0.015625f) {                                     // subnormal: step 2^-9
        int qv = (int)rintf(a * 512.0f);
        if (qv > 7) return (unsigned char)(sgn | 0x08);      // rounds up to min normal
        return (unsigned char)(sgn | qv);
    }
    unsigned ub = __builtin_bit_cast(unsigned, a);
    unsigned rr = ub + 0x7FFFFu + ((ub >> 20) & 1u);         // RNE at mantissa bit 20
    int E = (int)(rr >> 23) - 127 + 7;
    unsigned m = (rr >> 20) & 7u;
    if (E < 1)  { E = 0; m = 7; }                            // boundary safety
    if (E > 15) { E = 15; m = 6; }
    if (E == 15 && m == 7) m = 6;                            // avoid NaN encoding
    return (unsigned char)(sgn | ((unsigned)E << 3) | m);
}
template <bool HI>
static __device__ __forceinline__ unsigned cvt2_fp8(float a, float b, unsigned old) {
#if __has_builtin(__builtin_amdgcn_cvt_pk_fp8_f32)
    return (unsigned)__builtin_amdgcn_cvt_pk_fp8_f32(a, b, (int)old, HI);
#else
    unsigned p = (unsigned)f2e4m3_sw(a) | ((unsigned)f2e4m3_sw(b) << 8);
    return HI ? ((old & 0x0000FFFFu) | (p << 16)) : ((old & 0xFFFF0000u) | p);
#endif
}

static __device__ __forceinline__ float tanh_f(float x) {
    float ex = __expf(2.0f * x);
    return 1.0f - 2.0f * __builtin_amdgcn_rcpf(ex + 1.0f);
}

// k-permutation (shared by A-storage, B-fragments): fragment (s, qk=lane>>4, j)
// holds hidden index c = 128*(s>>2) + 16*j + 4*(s&3) + qk.  Bijection on [0,512).

// ---------------------------------------------------------------------------
// Prep 0: W_hx [256,512] f32 -> W_hx^T [512,256] bf16
// ---------------------------------------------------------------------------
__global__ void k_whxT(const float* __restrict__ Whx, unsigned short* __restrict__ WhxT) {
    int idx = blockIdx.x * 256 + threadIdx.x;
    int n = idx >> 8;
    int k = idx & 255;
    WhxT[n * 256 + k] = f2bf(Whx[k * 512 + n]);
}

// ---------------------------------------------------------------------------
// Prep 1: W_hh f32 -> Wf8: fp8 e4m3 MFMA B-fragments (k-permuted).
// Wf8 8-byte entry gid = ((w*16+s)*8+nb)*64 + l, byte j:
//   W_hh[c = 128*(s>>2) + 16*j + 4*(s&3) + (l>>4)][col = 128w + 16nb + (l&15)]
// ---------------------------------------------------------------------------
__global__ void k_wfrag8(const float* __restrict__ Whh, unsigned char* __restrict__ Wf8) {
    int gid = blockIdx.x * 256 + threadIdx.x;    // 32768
    int l = gid & 63, grp = gid >> 6;
    int nb = grp & 7, s = (grp >> 3) & 15, w = grp >> 7;
    int col = 128 * w + 16 * nb + (l & 15);
    int qk = l >> 4;
    float v[8];
#pragma unroll
    for (int j = 0; j < 8; ++j) {
        int c = 128 * (s >> 2) + 16 * j + 4 * (s & 3) + qk;
        v[j] = Whh[(size_t)c * 512 + col];
    }
    unsigned w0 = cvt2_fp8<false>(v[0], v[1], 0u); w0 = cvt2_fp8<true>(v[2], v[3], w0);
    unsigned w1 = cvt2_fp8<false>(v[4], v[5], 0u); w1 = cvt2_fp8<true>(v[6], v[7], w1);
    ((u32x2*)Wf8)[gid] = u32x2{w0, w1};
}

// ---------------------------------------------------------------------------
// Phase 1: Z = x @ W_hx + b_h, written in k_rnn's Zr layout:
// Zr block (t,cu,w) = 4096B at ((t*8+cu)*4+w)*4096, [g 0..3][m 0..63][q 0..7] f16,
// value(q) = z[t][16cu + (m>>4)*4 + (q&3)][128w + 16*(2g + (q>>2)) + (m&15)].
// ---------------------------------------------------------------------------
__global__ void __launch_bounds__(256) k_gemm1(const float* __restrict__ x,
                                               const unsigned short* __restrict__ WhxT,
                                               const float* __restrict__ bh,
                                               char* __restrict__ Zr) {
    __shared__ char smem[32768];
    unsigned short* Asm = (unsigned short*)smem;
    unsigned short* Bsm = (unsigned short*)(smem + 8192);

    const int tid = threadIdx.x;
    const int bid = blockIdx.x;
    const int nt = bid & 3, mt = bid >> 2;
    const int r0 = mt * 128, n0 = nt * 128;
    const int w  = tid >> 6, l = tid & 63;
    const int wm = (w >> 1) * 64, wn = (w & 1) * 64;
    const int lr = l & 15, lk = (l >> 4) * 8;

    const int arow = tid >> 2, akc = (tid & 3) * 8;
    const int bcol = tid >> 1, bkc = (tid & 1) * 16;

    f32x4 acc[4][4] = {};

    for (int kk = 0; kk < 256; kk += 32) {
#pragma unroll
        for (int half = 0; half < 2; ++half) {
            const int r = arow + half * 64;
            const float* ap = x + (size_t)(r0 + r) * 256 + kk + akc;
            float4 f0 = *(const float4*)ap;
            float4 f1 = *(const float4*)(ap + 4);
            uint4 av;
            av.x = (unsigned)f2bf(f0.x) | ((unsigned)f2bf(f0.y) << 16);
            av.y = (unsigned)f2bf(f0.z) | ((unsigned)f2bf(f0.w) << 16);
            av.z = (unsigned)f2bf(f1.x) | ((unsigned)f2bf(f1.y) << 16);
            av.w = (unsigned)f2bf(f1.z) | ((unsigned)f2bf(f1.w) << 16);
            *(uint4*)&Asm[r * 32 + akc] = av;
        }
        const unsigned short* bsrc = WhxT + (size_t)(n0 + bcol) * 256 + kk + bkc;
        uint4 bv0 = *(const uint4*)bsrc;
        uint4 bv1 = *(const uint4*)(bsrc + 8);
        *(uint4*)&Bsm[bcol * 32 + bkc] = bv0;
        *(uint4*)&Bsm[bcol * 32 + bkc + 8] = bv1;
        __syncthreads();

        s16x8 af[4], bf[4];
#pragma unroll
        for (int mi = 0; mi < 4; ++mi)
            af[mi] = *(const s16x8*)&Asm[(wm + mi * 16 + lr) * 32 + lk];
#pragma unroll
        for (int ni = 0; ni < 4; ++ni)
            bf[ni] = *(const s16x8*)&Bsm[(wn + ni * 16 + lr) * 32 + lk];
#pragma unroll
        for (int mi = 0; mi < 4; ++mi)
#pragma unroll
            for (int ni = 0; ni < 4; ++ni)
                acc[mi][ni] = __builtin_amdgcn_mfma_f32_16x16x32_bf16(af[mi], bf[ni], acc[mi][ni], 0, 0, 0);
        __syncthreads();
    }

    _Float16* Szr = (_Float16*)smem;   // [cu][g][m][q] = 32 KiB
#pragma unroll
    for (int mi = 0; mi < 4; ++mi)
#pragma unroll
        for (int ni = 0; ni < 4; ++ni) {
            const int col_l = wn + ni * 16 + lr;
            const float bhv = bh[n0 + col_l];
            const int g   = (col_l >> 5) & 3;
            const int qhi = ((col_l >> 4) & 1) * 4;
#pragma unroll
            for (int e = 0; e < 4; ++e) {
                const int b   = wm + mi * 16 + (l >> 4) * 4 + e;
                const int cu  = b >> 4;
                const int m_r = ((b & 15) >> 2) * 16 + lr;
                Szr[((cu * 4 + g) * 64 + m_r) * 8 + qhi + e] = (_Float16)(acc[mi][ni][e] + bhv);
            }
        }
    __syncthreads();
    {
        const uint4* srcv = (const uint4*)smem;
#pragma unroll
        for (int i = 0; i < 8; ++i) {
            const int o   = tid * 128 + i * 16;
            const int cuo = o >> 12;
            char* dst = Zr + ((size_t)((mt * 8 + cuo) * 4 + nt)) * 4096 + (o & 4095);
            *(uint4*)dst = srcv[o >> 4];
        }
    }
}

// ---------------------------------------------------------------------------
// Phase 2: fp8 MFMA recurrence. 8 WGs x 256 threads (4 waves, 1 wave/SIMD).
// WG cu: batch rows [16cu,16cu+16); wave w: cols [128w,128w+128).
// B (W_hh fp8): slices 0..13 pinned in AGPRs via asm "a" operands (224 regs),
// slices 14,15 in arch VGPRs. h in LDS as exact fp8 A-fragments (XOR-swizzled,
// full-BW b64 read/write), double-buffered; ONE barrier/step.
// ---------------------------------------------------------------------------
#define MM_A(C_, A_, B_) asm("v_mfma_f32_16x16x32_fp8_fp8 %0, %1, %2, %0" : "+v"(C_) : "v"(A_), "a"(B_))
#define MM_V(C_, A_, B_) asm("v_mfma_f32_16x16x32_fp8_fp8 %0, %1, %2, %0" : "+v"(C_) : "v"(A_), "v"(B_))

__global__
__attribute__((amdgpu_flat_work_group_size(256, 256), amdgpu_waves_per_eu(1, 1)))
void k_rnn(const unsigned char* __restrict__ Wf8,
           const char* __restrict__ Zr,
           float* __restrict__ hf) {
    __shared__ char hA[2][8192];   // h as fp8 A-fragments, double-buffered

    const int tid = threadIdx.x, cu = blockIdx.x;
    const int w = tid >> 6, l = tid & 63;
    const int r = l & 15, q = l >> 4;

    // ---- stationary B fragments ----
    u32x2 BA[14][8];   // slices 0..13 -> AGPR (asm "a")
    u32x2 BV[2][8];    // slices 14,15 -> arch VGPR
    {
        const u32x2* Wb = (const u32x2*)Wf8 + (size_t)(w * 16 * 8) * 64 + l;
#pragma unroll
        for (int s = 0; s < 14; ++s)
#pragma unroll
            for (int nb = 0; nb < 8; ++nb)
                BA[s][nb] = Wb[(s * 8 + nb) * 64];
#pragma unroll
        for (int s = 0; s < 2; ++s)
#pragma unroll
            for (int nb = 0; nb < 8; ++nb)
                BV[s][nb] = Wb[((14 + s) * 8 + nb) * 64];
    }

    // h0 = 0 (both buffers)
#pragma unroll
    for (int i = 0; i < 4; ++i)
        ((uint4*)hA)[i * 256 + tid] = uint4{0, 0, 0, 0};
    __syncthreads();

    const int l8 = l * 8;
    const int sW = 4 * w + (r >> 2);
    int wd[4];
#pragma unroll
    for (int e = 0; e < 4; ++e) {
        int ld = 4 * q + e + 16 * (r & 3);
        wd[e] = sW * 512 + ((ld ^ sW) << 3);
    }

    for (int t = 0; t < T_; ++t) {
        char* rb = &hA[t & 1][0];
        char* ob = &hA[(t & 1) ^ 1][0];

        // z for this step (f16, fragment-matched layout)
        const v8h* zb = (const v8h*)(Zr + (((size_t)t * 8 + cu) * 4 + w) * 4096);
        v8h zc[4];
#pragma unroll
        for (int g = 0; g < 4; ++g) zc[g] = zb[g * 64 + l];

        // A fragments: 16 x ds_read_b64 (XOR-swizzled, conflict-free)
        u32x2 av[16];
#pragma unroll
        for (int s = 0; s < 16; ++s)
            av[s] = *(const u32x2*)(rb + s * 512 + (l8 ^ ((s & 15) << 3)));

        f32x4 cc[8];
#pragma unroll
        for (int nb = 0; nb < 8; ++nb) cc[nb] = f32x4{0.f, 0.f, 0.f, 0.f};

        // MFMA: 4 independent chains per group (latency-hidden)
#pragma unroll
        for (int s = 0; s < 16; ++s)
#pragma unroll
            for (int nb = 0; nb < 4; ++nb) {
                if (s < 14) MM_A(cc[nb], av[s], BA[s][nb]);
                else        MM_V(cc[nb], av[s], BV[s - 14][nb]);
            }
#pragma unroll
        for (int s = 0; s < 16; ++s)
#pragma unroll
            for (int nb = 4; nb < 8; ++nb) {
                if (s < 14) MM_A(cc[nb], av[s], BA[s][nb]);
                else        MM_V(cc[nb], av[s], BV[s - 14][nb]);
            }

        // MFMA -> VALU hazard wall (asm MFMAs are opaque to the hazard recognizer)
        __builtin_amdgcn_sched_barrier(0);
        asm volatile("s_nop 7\n\ts_nop 7\n\ts_nop 3" ::);
        __builtin_amdgcn_sched_barrier(0);

        // epilogue: z + tanh -> fp8, 4 packed b64 writes into other buffer
        unsigned plo[4], phi[4];
#pragma unroll
        for (int e = 0; e < 4; ++e) {
            float h0 = tanh_f(cc[0][e] + (float)zc[0][e]);
            float h1 = tanh_f(cc[1][e] + (float)zc[0][4 + e]);
            float h2 = tanh_f(cc[2][e] + (float)zc[1][e]);
            float h3 = tanh_f(cc[3][e] + (float)zc[1][4 + e]);
            unsigned t0 = cvt2_fp8<false>(h0, h1, 0u);
            plo[e] = cvt2_fp8<true>(h2, h3, t0);
            if (t == T_ - 1) {
                size_t row = (size_t)(16 * cu + 4 * q + e) * 512 + 128 * w + r;
                hf[row + 0]  = h0; hf[row + 16] = h1;
                hf[row + 32] = h2; hf[row + 48] = h3;
            }
        }
#pragma unroll
        for (int e = 0; e < 4; ++e) {
            float h4 = tanh_f(cc[4][e] + (float)zc[2][e]);
            float h5 = tanh_f(cc[5][e] + (float)zc[2][4 + e]);
            float h6 = tanh_f(cc[6][e] + (float)zc[3][e]);
            float h7 = tanh_f(cc[7][e] + (float)zc[3][4 + e]);
            unsigned t1 = cvt2_fp8<false>(h4, h5, 0u);
            phi[e] = cvt2_fp8<true>(h6, h7, t1);
            if (t == T_ - 1) {
                size_t row = (size_t)(16 * cu + 4 * q + e) * 512 + 128 * w + r;
                hf[row + 64]  = h4; hf[row + 80]  = h5;
                hf[row + 96]  = h6; hf[row + 112] = h7;
            }
        }
#pragma unroll
        for (int e = 0; e < 4; ++e)
            *(u32x2*)(ob + wd[e]) = u32x2{plo[e], phi[e]};

        __syncthreads();
    }
}

// ---------------------------------------------------------------------------
// Phase 3: out = h_final @ W_ph + b_p   [128,512]@[512,10]
// ---------------------------------------------------------------------------
__global__ void k_out(const float* __restrict__ hf, const float* __restrict__ Wph,
                      const float* __restrict__ bp, float* __restrict__ out) {
    __shared__ float red[160];
    int b = blockIdx.x, t = threadIdx.x;
    if (t < 160) {
        int c = t >> 4, ks = (t & 15) * 32;
        float s = 0.f;
        for (int u = 0; u < 32; ++u)
            s += hf[b * H_ + ks + u] * Wph[(ks + u) * C_ + c];
        red[t] = s;
    }
    __syncthreads();
    if (t < C_) {
        float s = bp[t];
        for (int i = 0; i < 16; ++i) s += red[t * 16 + i];
        out[b * C_ + t] = s;
    }
}

// ---------------------------------------------------------------------------
extern "C" void kernel_launch(void* const* d_in, const int* in_sizes, int n_in,
                              void* d_out, int out_size, void* d_ws, size_t ws_size,
                              hipStream_t stream) {
    const float* x   = (const float*)d_in[0];   // [512,128,256]
    const float* Whx = (const float*)d_in[1];   // [256,512]
    const float* Whh = (const float*)d_in[2];   // [512,512]
    const float* Wph = (const float*)d_in[3];   // [512,10]
    const float* bh  = (const float*)d_in[4];   // [512]
    const float* bp  = (const float*)d_in[5];   // [10]
    float* out = (float*)d_out;                 // [128,10] f32

    char* ws = (char*)d_ws;
    unsigned short* WhxT = (unsigned short*)(ws);                    // 256 KiB
    unsigned char*  Wf8  = (unsigned char*)(ws + 262144);            // 256 KiB
    char*           Zr   = ws + 786432;                              // 64 MiB
    float*          hf   = (float*)(ws + 786432 + 67108864);         // 256 KiB

    hipLaunchKernelGGL(k_whxT,   dim3(512),  dim3(256), 0, stream, Whx, WhxT);
    hipLaunchKernelGGL(k_wfrag8, dim3(128),  dim3(256), 0, stream, Whh, Wf8);
    hipLaunchKernelGGL(k_gemm1,  dim3(2048), dim3(256), 0, stream, x, WhxT, bh, Zr);
    hipLaunchKernelGGL(k_rnn,    dim3(8),    dim3(256), 0, stream, Wf8, Zr, hf);
    hipLaunchKernelGGL(k_out,    dim3(128),  dim3(256), 0, stream, hf, Wph, bp, out);
}

// Round 10
// 826.537 us; speedup vs baseline: 3.0538x; 1.2243x over previous
//
#include <hip/hip_runtime.h>
#include <cstdint>
#include <cstddef>

#define T_ 512
#define B_ 128
#define D_ 256
#define H_ 512
#define C_ 10

typedef float  f32x4 __attribute__((ext_vector_type(4)));
typedef short  s16x8 __attribute__((ext_vector_type(8)));
typedef _Float16 v8h  __attribute__((ext_vector_type(8)));
typedef unsigned u32x2 __attribute__((ext_vector_type(2)));

static __device__ __forceinline__ unsigned short f2bf(float f) {
    unsigned u = __builtin_bit_cast(unsigned, f);
    unsigned r = u + 0x7FFFu + ((u >> 16) & 1u);
    return (unsigned short)(r >> 16);
}

// ---- fp8 e4m3fn encode (HW cvt if available, else software RNE) ----
static __device__ __forceinline__ unsigned char f2e4m3_sw(float f) {
    unsigned u = __builtin_bit_cast(unsigned, f);
    unsigned sgn = (u >> 24) & 0x80u;
    float a = fabsf(f);
    if (a != a) return (unsigned char)(sgn | 0x7E);
    if (a >= 448.0f) return (unsigned char)(sgn | 0x7E);
    if (a < 0.015625f) {
        int qv = (int)rintf(a * 512.0f);
        if (qv > 7) return (unsigned char)(sgn | 0x08);
        return (unsigned char)(sgn | qv);
    }
    unsigned ub = __builtin_bit_cast(unsigned, a);
    unsigned rr = ub + 0x7FFFFu + ((ub >> 20) & 1u);
    int E = (int)(rr >> 23) - 127 + 7;
    unsigned m = (rr >> 20) & 7u;
    if (E < 1)  { E = 0; m = 7; }
    if (E > 15) { E = 15; m = 6; }
    if (E == 15 && m == 7) m = 6;
    return (unsigned char)(sgn | ((unsigned)E << 3) | m);
}
template <bool HI>
static __device__ __forceinline__ unsigned cvt2_fp8(float a, float b, unsigned old) {
#if __has_builtin(__builtin_amdgcn_cvt_pk_fp8_f32)
    return (unsigned)__builtin_amdgcn_cvt_pk_fp8_f32(a, b, (int)old, HI);
#else
    unsigned p = (unsigned)f2e4m3_sw(a) | ((unsigned)f2e4m3_sw(b) << 8);
    return HI ? ((old & 0x0000FFFFu) | (p << 16)) : ((old & 0xFFFF0000u) | p);
#endif
}

static __device__ __forceinline__ float tanh_f(float x) {
    float ex = __expf(2.0f * x);
    return 1.0f - 2.0f * __builtin_amdgcn_rcpf(ex + 1.0f);
}

// k-permutation (shared by A-storage, B-fragments): fragment (s, qk=lane>>4, j)
// holds hidden index c = 128*(s>>2) + 16*j + 4*(s&3) + qk.  Bijection on [0,512).

// ---------------------------------------------------------------------------
// Prep 0: W_hx [256,512] f32 -> W_hx^T [512,256] bf16
// ---------------------------------------------------------------------------
__global__ void k_whxT(const float* __restrict__ Whx, unsigned short* __restrict__ WhxT) {
    int idx = blockIdx.x * 256 + threadIdx.x;
    int n = idx >> 8;
    int k = idx & 255;
    WhxT[n * 256 + k] = f2bf(Whx[k * 512 + n]);
}

// ---------------------------------------------------------------------------
// Prep 1: W_hh f32 -> Wf8: fp8 e4m3 MFMA B-fragments (k-permuted).
// Wf8 8-byte entry gid = ((W*16+s)*8+nb)*64 + l, byte j:
//   W_hh[c = 128*(s>>2) + 16*j + 4*(s&3) + (l>>4)][col = 128W + 16nb + (l&15)]
// ---------------------------------------------------------------------------
__global__ void k_wfrag8(const float* __restrict__ Whh, unsigned char* __restrict__ Wf8) {
    int gid = blockIdx.x * 256 + threadIdx.x;    // 32768
    int l = gid & 63, grp = gid >> 6;
    int nb = grp & 7, s = (grp >> 3) & 15, w = grp >> 7;
    int col = 128 * w + 16 * nb + (l & 15);
    int qk = l >> 4;
    float v[8];
#pragma unroll
    for (int j = 0; j < 8; ++j) {
        int c = 128 * (s >> 2) + 16 * j + 4 * (s & 3) + qk;
        v[j] = Whh[(size_t)c * 512 + col];
    }
    unsigned w0 = cvt2_fp8<false>(v[0], v[1], 0u); w0 = cvt2_fp8<true>(v[2], v[3], w0);
    unsigned w1 = cvt2_fp8<false>(v[4], v[5], 0u); w1 = cvt2_fp8<true>(v[6], v[7], w1);
    ((u32x2*)Wf8)[gid] = u32x2{w0, w1};
}

// ---------------------------------------------------------------------------
// Phase 1: Z = x @ W_hx + b_h, written in k_rnn's Zr layout:
// Zr block (t,cu,W) = 4096B at ((t*8+cu)*4+W)*4096, [g 0..3][m 0..63][q 0..7] f16,
// value(q) = z[t][16cu + (m>>4)*4 + (q&3)][128W + 16*(2g + (q>>2)) + (m&15)].
// ---------------------------------------------------------------------------
__global__ void __launch_bounds__(256) k_gemm1(const float* __restrict__ x,
                                               const unsigned short* __restrict__ WhxT,
                                               const float* __restrict__ bh,
                                               char* __restrict__ Zr) {
    __shared__ char smem[32768];
    unsigned short* Asm = (unsigned short*)smem;
    unsigned short* Bsm = (unsigned short*)(smem + 8192);

    const int tid = threadIdx.x;
    const int bid = blockIdx.x;
    const int nt = bid & 3, mt = bid >> 2;
    const int r0 = mt * 128, n0 = nt * 128;
    const int w  = tid >> 6, l = tid & 63;
    const int wm = (w >> 1) * 64, wn = (w & 1) * 64;
    const int lr = l & 15, lk = (l >> 4) * 8;

    const int arow = tid >> 2, akc = (tid & 3) * 8;
    const int bcol = tid >> 1, bkc = (tid & 1) * 16;

    f32x4 acc[4][4] = {};

    for (int kk = 0; kk < 256; kk += 32) {
#pragma unroll
        for (int half = 0; half < 2; ++half) {
            const int r = arow + half * 64;
            const float* ap = x + (size_t)(r0 + r) * 256 + kk + akc;
            float4 f0 = *(const float4*)ap;
            float4 f1 = *(const float4*)(ap + 4);
            uint4 av;
            av.x = (unsigned)f2bf(f0.x) | ((unsigned)f2bf(f0.y) << 16);
            av.y = (unsigned)f2bf(f0.z) | ((unsigned)f2bf(f0.w) << 16);
            av.z = (unsigned)f2bf(f1.x) | ((unsigned)f2bf(f1.y) << 16);
            av.w = (unsigned)f2bf(f1.z) | ((unsigned)f2bf(f1.w) << 16);
            *(uint4*)&Asm[r * 32 + akc] = av;
        }
        const unsigned short* bsrc = WhxT + (size_t)(n0 + bcol) * 256 + kk + bkc;
        uint4 bv0 = *(const uint4*)bsrc;
        uint4 bv1 = *(const uint4*)(bsrc + 8);
        *(uint4*)&Bsm[bcol * 32 + bkc] = bv0;
        *(uint4*)&Bsm[bcol * 32 + bkc + 8] = bv1;
        __syncthreads();

        s16x8 af[4], bf[4];
#pragma unroll
        for (int mi = 0; mi < 4; ++mi)
            af[mi] = *(const s16x8*)&Asm[(wm + mi * 16 + lr) * 32 + lk];
#pragma unroll
        for (int ni = 0; ni < 4; ++ni)
            bf[ni] = *(const s16x8*)&Bsm[(wn + ni * 16 + lr) * 32 + lk];
#pragma unroll
        for (int mi = 0; mi < 4; ++mi)
#pragma unroll
            for (int ni = 0; ni < 4; ++ni)
                acc[mi][ni] = __builtin_amdgcn_mfma_f32_16x16x32_bf16(af[mi], bf[ni], acc[mi][ni], 0, 0, 0);
        __syncthreads();
    }

    _Float16* Szr = (_Float16*)smem;   // [cu][g][m][q] = 32 KiB
#pragma unroll
    for (int mi = 0; mi < 4; ++mi)
#pragma unroll
        for (int ni = 0; ni < 4; ++ni) {
            const int col_l = wn + ni * 16 + lr;
            const float bhv = bh[n0 + col_l];
            const int g   = (col_l >> 5) & 3;
            const int qhi = ((col_l >> 4) & 1) * 4;
#pragma unroll
            for (int e = 0; e < 4; ++e) {
                const int b   = wm + mi * 16 + (l >> 4) * 4 + e;
                const int cu  = b >> 4;
                const int m_r = ((b & 15) >> 2) * 16 + lr;
                Szr[((cu * 4 + g) * 64 + m_r) * 8 + qhi + e] = (_Float16)(acc[mi][ni][e] + bhv);
            }
        }
    __syncthreads();
    {
        const uint4* srcv = (const uint4*)smem;
#pragma unroll
        for (int i = 0; i < 8; ++i) {
            const int o   = tid * 128 + i * 16;
            const int cuo = o >> 12;
            char* dst = Zr + ((size_t)((mt * 8 + cuo) * 4 + nt)) * 4096 + (o & 4095);
            *(uint4*)dst = srcv[o >> 4];
        }
    }
}

// ---------------------------------------------------------------------------
// Phase 2: fp8 MFMA recurrence. 8 WGs x 512 threads (8 waves, 2 waves/SIMD).
// WG cu: batch rows [16cu,16cu+16). Wave w8: col block W=w8>>1 (128 cols),
// nb half = w8&1 (4 of 8 nb tiles) -> B = 16 slices x 4 nb x 2 regs = 128 AGPR
// per wave; 2 waves/SIMD fit (128 AGPR + <=128 arch each). Wave-level
// co-scheduling hides MFMA latency / VALU epilogue / LDS. z prefetched one
// step ahead. h double-buffered fp8 A-fragments in LDS; ONE barrier/step.
// ---------------------------------------------------------------------------
#define MM_A(C_, A_, B_) asm("v_mfma_f32_16x16x32_fp8_fp8 %0, %1, %2, %0" : "+v"(C_) : "v"(A_), "a"(B_))

__global__
__attribute__((amdgpu_flat_work_group_size(512, 512), amdgpu_waves_per_eu(2, 2)))
void k_rnn(const unsigned char* __restrict__ Wf8,
           const char* __restrict__ Zr,
           float* __restrict__ hf) {
    __shared__ char hA[2][8192];   // h as fp8 A-fragments, double-buffered

    const int tid = threadIdx.x, cu = blockIdx.x;
    const int w8 = tid >> 6;          // wave 0..7
    const int W  = w8 >> 1;           // col block 0..3 (128 cols)
    const int hf4 = w8 & 1;           // nb half: nb = 4*hf4 + j
    const int l = tid & 63;
    const int r = l & 15, q = l >> 4;

    // ---- stationary B fragments: 16 slices x 4 nb -> 128 AGPRs ----
    u32x2 BA[16][4];
    {
        const u32x2* Wb = (const u32x2*)Wf8 + (size_t)(W * 16 * 8) * 64 + l;
#pragma unroll
        for (int s = 0; s < 16; ++s)
#pragma unroll
            for (int j = 0; j < 4; ++j)
                BA[s][j] = Wb[(s * 8 + hf4 * 4 + j) * 64];
    }

    // h0 = 0 (both buffers): 1024 uint4, 512 threads -> 2 each
    ((uint4*)hA)[tid]       = uint4{0, 0, 0, 0};
    ((uint4*)hA)[512 + tid] = uint4{0, 0, 0, 0};
    __syncthreads();

    const int l8 = l * 8;
    const int sW = 4 * W + (r >> 2);
    int wd[4];
#pragma unroll
    for (int e = 0; e < 4; ++e) {
        int ld = 4 * q + e + 16 * (r & 3);
        wd[e] = sW * 512 + (((ld ^ sW) << 3) | (hf4 * 4));
    }

    // z for t=0 (this wave's 2 of 4 g-blocks)
    v8h zl[2];
    {
        const v8h* zp = (const v8h*)(Zr + ((size_t)cu * 4 + W) * 4096);
        zl[0] = zp[(2 * hf4 + 0) * 64 + l];
        zl[1] = zp[(2 * hf4 + 1) * 64 + l];
    }

    for (int t = 0; t < T_; ++t) {
        char* rb = &hA[t & 1][0];
        char* ob = &hA[(t & 1) ^ 1][0];

        // A fragments: 16 x ds_read_b64 (XOR-swizzled)
        u32x2 av[16];
#pragma unroll
        for (int s = 0; s < 16; ++s)
            av[s] = *(const u32x2*)(rb + s * 512 + (l8 ^ (s << 3)));

        // prefetch z for t+1 (latency hidden under this step's MFMA+epilogue)
        v8h zn[2];
        {
            int tn = (t + 1 < T_) ? t + 1 : t;
            const v8h* zp = (const v8h*)(Zr + (((size_t)tn * 8 + cu) * 4 + W) * 4096);
            zn[0] = zp[(2 * hf4 + 0) * 64 + l];
            zn[1] = zp[(2 * hf4 + 1) * 64 + l];
        }

        f32x4 cc[4];
#pragma unroll
        for (int j = 0; j < 4; ++j) cc[j] = f32x4{0.f, 0.f, 0.f, 0.f};

        // 64 MFMA, 4 interleaved chains (gap 4 covers MFMA latency)
#pragma unroll
        for (int s = 0; s < 16; ++s)
#pragma unroll
            for (int j = 0; j < 4; ++j)
                MM_A(cc[j], av[s], BA[s][j]);

        // MFMA -> VALU hazard wall (asm MFMAs opaque to hazard recognizer)
        __builtin_amdgcn_sched_barrier(0);
        asm volatile("s_nop 7\n\ts_nop 7\n\ts_nop 3" ::);
        __builtin_amdgcn_sched_barrier(0);

        // epilogue: z + tanh -> fp8, 4 packed b32 writes into other buffer
#pragma unroll
        for (int e = 0; e < 4; ++e) {
            float h0 = tanh_f(cc[0][e] + (float)zl[0][e]);
            float h1 = tanh_f(cc[1][e] + (float)zl[0][4 + e]);
            float h2 = tanh_f(cc[2][e] + (float)zl[1][e]);
            float h3 = tanh_f(cc[3][e] + (float)zl[1][4 + e]);
            unsigned p = cvt2_fp8<false>(h0, h1, 0u);
            p = cvt2_fp8<true>(h2, h3, p);
            *(unsigned*)(ob + wd[e]) = p;
            if (t == T_ - 1) {
                size_t row = (size_t)(16 * cu + 4 * q + e) * 512 + 128 * W + 64 * hf4 + r;
                hf[row + 0]  = h0; hf[row + 16] = h1;
                hf[row + 32] = h2; hf[row + 48] = h3;
            }
        }
        zl[0] = zn[0]; zl[1] = zn[1];
        __syncthreads();
    }
}

// ---------------------------------------------------------------------------
// Phase 3: out = h_final @ W_ph + b_p   [128,512]@[512,10]
// ---------------------------------------------------------------------------
__global__ void k_out(const float* __restrict__ hf, const float* __restrict__ Wph,
                      const float* __restrict__ bp, float* __restrict__ out) {
    __shared__ float red[160];
    int b = blockIdx.x, t = threadIdx.x;
    if (t < 160) {
        int c = t >> 4, ks = (t & 15) * 32;
        float s = 0.f;
        for (int u = 0; u < 32; ++u)
            s += hf[b * H_ + ks + u] * Wph[(ks + u) * C_ + c];
        red[t] = s;
    }
    __syncthreads();
    if (t < C_) {
        float s = bp[t];
        for (int i = 0; i < 16; ++i) s += red[t * 16 + i];
        out[b * C_ + t] = s;
    }
}

// ---------------------------------------------------------------------------
extern "C" void kernel_launch(void* const* d_in, const int* in_sizes, int n_in,
                              void* d_out, int out_size, void* d_ws, size_t ws_size,
                              hipStream_t stream) {
    const float* x   = (const float*)d_in[0];   // [512,128,256]
    const float* Whx = (const float*)d_in[1];   // [256,512]
    const float* Whh = (const float*)d_in[2];   // [512,512]
    const float* Wph = (const float*)d_in[3];   // [512,10]
    const float* bh  = (const float*)d_in[4];   // [512]
    const float* bp  = (const float*)d_in[5];   // [10]
    float* out = (float*)d_out;                 // [128,10] f32

    char* ws = (char*)d_ws;
    unsigned short* WhxT = (unsigned short*)(ws);                    // 256 KiB
    unsigned char*  Wf8  = (unsigned char*)(ws + 262144);            // 256 KiB
    char*           Zr   = ws + 786432;                              // 64 MiB
    float*          hf   = (float*)(ws + 786432 + 67108864);         // 256 KiB

    hipLaunchKernelGGL(k_whxT,   dim3(512),  dim3(256), 0, stream, Whx, WhxT);
    hipLaunchKernelGGL(k_wfrag8, dim3(128),  dim3(256), 0, stream, Whh, Wf8);
    hipLaunchKernelGGL(k_gemm1,  dim3(2048), dim3(256), 0, stream, x, WhxT, bh, Zr);
    hipLaunchKernelGGL(k_rnn,    dim3(8),    dim3(512), 0, stream, Wf8, Zr, hf);
    hipLaunchKernelGGL(k_out,    dim3(128),  dim3(256), 0, stream, hf, Wph, bp, out);
}

// Round 11
// 826.183 us; speedup vs baseline: 3.0551x; 1.0004x over previous
//
#include <hip/hip_runtime.h>
#include <cstdint>
#include <cstddef>

#define T_ 512
#define B_ 128
#define D_ 256
#define H_ 512
#define C_ 10

typedef float  f32x4 __attribute__((ext_vector_type(4)));
typedef short  s16x8 __attribute__((ext_vector_type(8)));
typedef _Float16 v8h  __attribute__((ext_vector_type(8)));
typedef unsigned u32x2 __attribute__((ext_vector_type(2)));

static __device__ __forceinline__ unsigned short f2bf(float f) {
    unsigned u = __builtin_bit_cast(unsigned, f);
    unsigned r = u + 0x7FFFu + ((u >> 16) & 1u);
    return (unsigned short)(r >> 16);
}

// ---- fp8 e4m3fn encode (HW cvt if available, else software RNE) ----
static __device__ __forceinline__ unsigned char f2e4m3_sw(float f) {
    unsigned u = __builtin_bit_cast(unsigned, f);
    unsigned sgn = (u >> 24) & 0x80u;
    float a = fabsf(f);
    if (a != a) return (unsigned char)(sgn | 0x7E);
    if (a >= 448.0f) return (unsigned char)(sgn | 0x7E);
    if (a < 0.015625f) {
        int qv = (int)rintf(a * 512.0f);
        if (qv > 7) return (unsigned char)(sgn | 0x08);
        return (unsigned char)(sgn | qv);
    }
    unsigned ub = __builtin_bit_cast(unsigned, a);
    unsigned rr = ub + 0x7FFFFu + ((ub >> 20) & 1u);
    int E = (int)(rr >> 23) - 127 + 7;
    unsigned m = (rr >> 20) & 7u;
    if (E < 1)  { E = 0; m = 7; }
    if (E > 15) { E = 15; m = 6; }
    if (E == 15 && m == 7) m = 6;
    return (unsigned char)(sgn | ((unsigned)E << 3) | m);
}
template <bool HI>
static __device__ __forceinline__ unsigned cvt2_fp8(float a, float b, unsigned old) {
#if __has_builtin(__builtin_amdgcn_cvt_pk_fp8_f32)
    return (unsigned)__builtin_amdgcn_cvt_pk_fp8_f32(a, b, (int)old, HI);
#else
    unsigned p = (unsigned)f2e4m3_sw(a) | ((unsigned)f2e4m3_sw(b) << 8);
    return HI ? ((old & 0x0000FFFFu) | (p << 16)) : ((old & 0xFFFF0000u) | p);
#endif
}

static __device__ __forceinline__ float tanh_f(float x) {
    float ex = __expf(2.0f * x);
    return 1.0f - 2.0f * __builtin_amdgcn_rcpf(ex + 1.0f);
}

// k-permutation (shared by A-storage, B-fragments): fragment (s, qk=lane>>4, j)
// holds hidden index c = 128*(s>>2) + 16*j + 4*(s&3) + qk.  Bijection on [0,512).

// ---------------------------------------------------------------------------
// Prep 0: W_hx [256,512] f32 -> W_hx^T [512,256] bf16
// ---------------------------------------------------------------------------
__global__ void k_whxT(const float* __restrict__ Whx, unsigned short* __restrict__ WhxT) {
    int idx = blockIdx.x * 256 + threadIdx.x;
    int n = idx >> 8;
    int k = idx & 255;
    WhxT[n * 256 + k] = f2bf(Whx[k * 512 + n]);
}

// ---------------------------------------------------------------------------
// Prep 1: W_hh f32 -> Wf8: fp8 e4m3 MFMA B-fragments (k-permuted).
// Wf8 8-byte entry gid = ((W*16+s)*8+nb)*64 + l, byte j:
//   W_hh[c = 128*(s>>2) + 16*j + 4*(s&3) + (l>>4)][col = 128W + 16nb + (l&15)]
// ---------------------------------------------------------------------------
__global__ void k_wfrag8(const float* __restrict__ Whh, unsigned char* __restrict__ Wf8) {
    int gid = blockIdx.x * 256 + threadIdx.x;    // 32768
    int l = gid & 63, grp = gid >> 6;
    int nb = grp & 7, s = (grp >> 3) & 15, w = grp >> 7;
    int col = 128 * w + 16 * nb + (l & 15);
    int qk = l >> 4;
    float v[8];
#pragma unroll
    for (int j = 0; j < 8; ++j) {
        int c = 128 * (s >> 2) + 16 * j + 4 * (s & 3) + qk;
        v[j] = Whh[(size_t)c * 512 + col];
    }
    unsigned w0 = cvt2_fp8<false>(v[0], v[1], 0u); w0 = cvt2_fp8<true>(v[2], v[3], w0);
    unsigned w1 = cvt2_fp8<false>(v[4], v[5], 0u); w1 = cvt2_fp8<true>(v[6], v[7], w1);
    ((u32x2*)Wf8)[gid] = u32x2{w0, w1};
}

// ---------------------------------------------------------------------------
// Phase 1: Z = x @ W_hx + b_h, written in k_rnn's Zr layout:
// Zr block (t,cu,W) = 4096B at ((t*8+cu)*4+W)*4096, [g 0..3][m 0..63][q 0..7] f16,
// value(q) = z[t][16cu + (m>>4)*4 + (q&3)][128W + 16*(2g + (q>>2)) + (m&15)].
// ---------------------------------------------------------------------------
__global__ void __launch_bounds__(256) k_gemm1(const float* __restrict__ x,
                                               const unsigned short* __restrict__ WhxT,
                                               const float* __restrict__ bh,
                                               char* __restrict__ Zr) {
    __shared__ char smem[32768];
    unsigned short* Asm = (unsigned short*)smem;
    unsigned short* Bsm = (unsigned short*)(smem + 8192);

    const int tid = threadIdx.x;
    const int bid = blockIdx.x;
    const int nt = bid & 3, mt = bid >> 2;
    const int r0 = mt * 128, n0 = nt * 128;
    const int w  = tid >> 6, l = tid & 63;
    const int wm = (w >> 1) * 64, wn = (w & 1) * 64;
    const int lr = l & 15, lk = (l >> 4) * 8;

    const int arow = tid >> 2, akc = (tid & 3) * 8;
    const int bcol = tid >> 1, bkc = (tid & 1) * 16;

    f32x4 acc[4][4] = {};

    for (int kk = 0; kk < 256; kk += 32) {
#pragma unroll
        for (int half = 0; half < 2; ++half) {
            const int r = arow + half * 64;
            const float* ap = x + (size_t)(r0 + r) * 256 + kk + akc;
            float4 f0 = *(const float4*)ap;
            float4 f1 = *(const float4*)(ap + 4);
            uint4 av;
            av.x = (unsigned)f2bf(f0.x) | ((unsigned)f2bf(f0.y) << 16);
            av.y = (unsigned)f2bf(f0.z) | ((unsigned)f2bf(f0.w) << 16);
            av.z = (unsigned)f2bf(f1.x) | ((unsigned)f2bf(f1.y) << 16);
            av.w = (unsigned)f2bf(f1.z) | ((unsigned)f2bf(f1.w) << 16);
            *(uint4*)&Asm[r * 32 + akc] = av;
        }
        const unsigned short* bsrc = WhxT + (size_t)(n0 + bcol) * 256 + kk + bkc;
        uint4 bv0 = *(const uint4*)bsrc;
        uint4 bv1 = *(const uint4*)(bsrc + 8);
        *(uint4*)&Bsm[bcol * 32 + bkc] = bv0;
        *(uint4*)&Bsm[bcol * 32 + bkc + 8] = bv1;
        __syncthreads();

        s16x8 af[4], bf[4];
#pragma unroll
        for (int mi = 0; mi < 4; ++mi)
            af[mi] = *(const s16x8*)&Asm[(wm + mi * 16 + lr) * 32 + lk];
#pragma unroll
        for (int ni = 0; ni < 4; ++ni)
            bf[ni] = *(const s16x8*)&Bsm[(wn + ni * 16 + lr) * 32 + lk];
#pragma unroll
        for (int mi = 0; mi < 4; ++mi)
#pragma unroll
            for (int ni = 0; ni < 4; ++ni)
                acc[mi][ni] = __builtin_amdgcn_mfma_f32_16x16x32_bf16(af[mi], bf[ni], acc[mi][ni], 0, 0, 0);
        __syncthreads();
    }

    _Float16* Szr = (_Float16*)smem;   // [cu][g][m][q] = 32 KiB
#pragma unroll
    for (int mi = 0; mi < 4; ++mi)
#pragma unroll
        for (int ni = 0; ni < 4; ++ni) {
            const int col_l = wn + ni * 16 + lr;
            const float bhv = bh[n0 + col_l];
            const int g   = (col_l >> 5) & 3;
            const int qhi = ((col_l >> 4) & 1) * 4;
#pragma unroll
            for (int e = 0; e < 4; ++e) {
                const int b   = wm + mi * 16 + (l >> 4) * 4 + e;
                const int cu  = b >> 4;
                const int m_r = ((b & 15) >> 2) * 16 + lr;
                Szr[((cu * 4 + g) * 64 + m_r) * 8 + qhi + e] = (_Float16)(acc[mi][ni][e] + bhv);
            }
        }
    __syncthreads();
    {
        const uint4* srcv = (const uint4*)smem;
#pragma unroll
        for (int i = 0; i < 8; ++i) {
            const int o   = tid * 128 + i * 16;
            const int cuo = o >> 12;
            char* dst = Zr + ((size_t)((mt * 8 + cuo) * 4 + nt)) * 4096 + (o & 4095);
            *(uint4*)dst = srcv[o >> 4];
        }
    }
}

// ---------------------------------------------------------------------------
// Phase 2: fp8 MFMA recurrence. 8 WGs x 512 threads (8 waves, 2 waves/SIMD).
// WG cu: batch rows [16cu,16cu+16). Wave w8: col block W=w8>>1 (128 cols),
// nb half = w8&1 (4 of 8 nb tiles) -> B = 16 slices x 4 nb x 2 regs = 128 AGPR
// per wave; 2 waves/SIMD fit (128 AGPR + <=128 arch each). Wave-level
// co-scheduling hides MFMA latency / VALU epilogue / LDS. z prefetched one
// step ahead. h double-buffered fp8 A-fragments in LDS; ONE barrier/step.
// ---------------------------------------------------------------------------
#define MM_A(C_, A_, B_) asm("v_mfma_f32_16x16x32_fp8_fp8 %0, %1, %2, %0" : "+v"(C_) : "v"(A_), "a"(B_))

__global__
__attribute__((amdgpu_flat_work_group_size(512, 512), amdgpu_waves_per_eu(2, 2)))
void k_rnn(const unsigned char* __restrict__ Wf8,
           const char* __restrict__ Zr,
           float* __restrict__ hf) {
    __shared__ char hA[2][8192];   // h as fp8 A-fragments, double-buffered

    const int tid = threadIdx.x, cu = blockIdx.x;
    const int w8 = tid >> 6;          // wave 0..7
    const int W  = w8 >> 1;           // col block 0..3 (128 cols)
    const int hf4 = w8 & 1;           // nb half: nb = 4*hf4 + j
    const int l = tid & 63;
    const int r = l & 15, q = l >> 4;

    // ---- stationary B fragments: 16 slices x 4 nb -> 128 AGPRs ----
    u32x2 BA[16][4];
    {
        const u32x2* Wb = (const u32x2*)Wf8 + (size_t)(W * 16 * 8) * 64 + l;
#pragma unroll
        for (int s = 0; s < 16; ++s)
#pragma unroll
            for (int j = 0; j < 4; ++j)
                BA[s][j] = Wb[(s * 8 + hf4 * 4 + j) * 64];
    }

    // h0 = 0 (both buffers): 1024 uint4, 512 threads -> 2 each
    ((uint4*)hA)[tid]       = uint4{0, 0, 0, 0};
    ((uint4*)hA)[512 + tid] = uint4{0, 0, 0, 0};
    __syncthreads();

    const int l8 = l * 8;
    const int sW = 4 * W + (r >> 2);
    int wd[4];
#pragma unroll
    for (int e = 0; e < 4; ++e) {
        int ld = 4 * q + e + 16 * (r & 3);
        wd[e] = sW * 512 + (((ld ^ sW) << 3) | (hf4 * 4));
    }

    // z for t=0 (this wave's 2 of 4 g-blocks)
    v8h zl[2];
    {
        const v8h* zp = (const v8h*)(Zr + ((size_t)cu * 4 + W) * 4096);
        zl[0] = zp[(2 * hf4 + 0) * 64 + l];
        zl[1] = zp[(2 * hf4 + 1) * 64 + l];
    }

    for (int t = 0; t < T_; ++t) {
        char* rb = &hA[t & 1][0];
        char* ob = &hA[(t & 1) ^ 1][0];

        // A fragments: 16 x ds_read_b64 (XOR-swizzled)
        u32x2 av[16];
#pragma unroll
        for (int s = 0; s < 16; ++s)
            av[s] = *(const u32x2*)(rb + s * 512 + (l8 ^ (s << 3)));

        // prefetch z for t+1 (latency hidden under this step's MFMA+epilogue)
        v8h zn[2];
        {
            int tn = (t + 1 < T_) ? t + 1 : t;
            const v8h* zp = (const v8h*)(Zr + (((size_t)tn * 8 + cu) * 4 + W) * 4096);
            zn[0] = zp[(2 * hf4 + 0) * 64 + l];
            zn[1] = zp[(2 * hf4 + 1) * 64 + l];
        }

        f32x4 cc[4];
#pragma unroll
        for (int j = 0; j < 4; ++j) cc[j] = f32x4{0.f, 0.f, 0.f, 0.f};

        // 64 MFMA, 4 interleaved chains (gap 4 covers MFMA latency)
#pragma unroll
        for (int s = 0; s < 16; ++s)
#pragma unroll
            for (int j = 0; j < 4; ++j)
                MM_A(cc[j], av[s], BA[s][j]);

        // MFMA -> VALU hazard wall (asm MFMAs opaque to hazard recognizer)
        __builtin_amdgcn_sched_barrier(0);
        asm volatile("s_nop 7\n\ts_nop 7\n\ts_nop 3" ::);
        __builtin_amdgcn_sched_barrier(0);

        // epilogue: z + tanh -> fp8, 4 packed b32 writes into other buffer
#pragma unroll
        for (int e = 0; e < 4; ++e) {
            float h0 = tanh_f(cc[0][e] + (float)zl[0][e]);
            float h1 = tanh_f(cc[1][e] + (float)zl[0][4 + e]);
            float h2 = tanh_f(cc[2][e] + (float)zl[1][e]);
            float h3 = tanh_f(cc[3][e] + (float)zl[1][4 + e]);
            unsigned p = cvt2_fp8<false>(h0, h1, 0u);
            p = cvt2_fp8<true>(h2, h3, p);
            *(unsigned*)(ob + wd[e]) = p;
            if (t == T_ - 1) {
                size_t row = (size_t)(16 * cu + 4 * q + e) * 512 + 128 * W + 64 * hf4 + r;
                hf[row + 0]  = h0; hf[row + 16] = h1;
                hf[row + 32] = h2; hf[row + 48] = h3;
            }
        }
        zl[0] = zn[0]; zl[1] = zn[1];
        __syncthreads();
    }
}

// ---------------------------------------------------------------------------
// Phase 3: out = h_final @ W_ph + b_p   [128,512]@[512,10]
// ---------------------------------------------------------------------------
__global__ void k_out(const float* __restrict__ hf, const float* __restrict__ Wph,
                      const float* __restrict__ bp, float* __restrict__ out) {
    __shared__ float red[160];
    int b = blockIdx.x, t = threadIdx.x;
    if (t < 160) {
        int c = t >> 4, ks = (t & 15) * 32;
        float s = 0.f;
        for (int u = 0; u < 32; ++u)
            s += hf[b * H_ + ks + u] * Wph[(ks + u) * C_ + c];
        red[t] = s;
    }
    __syncthreads();
    if (t < C_) {
        float s = bp[t];
        for (int i = 0; i < 16; ++i) s += red[t * 16 + i];
        out[b * C_ + t] = s;
    }
}

// ---------------------------------------------------------------------------
extern "C" void kernel_launch(void* const* d_in, const int* in_sizes, int n_in,
                              void* d_out, int out_size, void* d_ws, size_t ws_size,
                              hipStream_t stream) {
    const float* x   = (const float*)d_in[0];   // [512,128,256]
    const float* Whx = (const float*)d_in[1];   // [256,512]
    const float* Whh = (const float*)d_in[2];   // [512,512]
    const float* Wph = (const float*)d_in[3];   // [512,10]
    const float* bh  = (const float*)d_in[4];   // [512]
    const float* bp  = (const float*)d_in[5];   // [10]
    float* out = (float*)d_out;                 // [128,10] f32

    char* ws = (char*)d_ws;
    unsigned short* WhxT = (unsigned short*)(ws);                    // 256 KiB
    unsigned char*  Wf8  = (unsigned char*)(ws + 262144);            // 256 KiB
    char*           Zr   = ws + 786432;                              // 64 MiB
    float*          hf   = (float*)(ws + 786432 + 67108864);         // 256 KiB

    hipLaunchKernelGGL(k_whxT,   dim3(512),  dim3(256), 0, stream, Whx, WhxT);
    hipLaunchKernelGGL(k_wfrag8, dim3(128),  dim3(256), 0, stream, Whh, Wf8);
    hipLaunchKernelGGL(k_gemm1,  dim3(2048), dim3(256), 0, stream, x, WhxT, bh, Zr);
    hipLaunchKernelGGL(k_rnn,    dim3(8),    dim3(512), 0, stream, Wf8, Zr, hf);
    hipLaunchKernelGGL(k_out,    dim3(128),  dim3(256), 0, stream, hf, Wph, bp, out);
}

// Round 12
// 659.951 us; speedup vs baseline: 3.8247x; 1.2519x over previous
//
#include <hip/hip_runtime.h>
#include <cstdint>
#include <cstddef>

#define T_ 512
#define B_ 128
#define D_ 256
#define H_ 512
#define C_ 10

typedef float  f32x4 __attribute__((ext_vector_type(4)));
typedef short  s16x8 __attribute__((ext_vector_type(8)));
typedef _Float16 v8h  __attribute__((ext_vector_type(8)));
typedef unsigned u32x8 __attribute__((ext_vector_type(8)));

static __device__ __forceinline__ unsigned short f2bf(float f) {
    unsigned u = __builtin_bit_cast(unsigned, f);
    unsigned r = u + 0x7FFFu + ((u >> 16) & 1u);
    return (unsigned short)(r >> 16);
}

// ---- fp8 e4m3fn encode (HW cvt if available, else software RNE) ----
static __device__ __forceinline__ unsigned char f2e4m3_sw(float f) {
    unsigned u = __builtin_bit_cast(unsigned, f);
    unsigned sgn = (u >> 24) & 0x80u;
    float a = fabsf(f);
    if (a != a) return (unsigned char)(sgn | 0x7E);
    if (a >= 448.0f) return (unsigned char)(sgn | 0x7E);
    if (a < 0.015625f) {
        int qv = (int)rintf(a * 512.0f);
        if (qv > 7) return (unsigned char)(sgn | 0x08);
        return (unsigned char)(sgn | qv);
    }
    unsigned ub = __builtin_bit_cast(unsigned, a);
    unsigned rr = ub + 0x7FFFFu + ((ub >> 20) & 1u);
    int E = (int)(rr >> 23) - 127 + 7;
    unsigned m = (rr >> 20) & 7u;
    if (E < 1)  { E = 0; m = 7; }
    if (E > 15) { E = 15; m = 6; }
    if (E == 15 && m == 7) m = 6;
    return (unsigned char)(sgn | ((unsigned)E << 3) | m);
}
template <bool HI>
static __device__ __forceinline__ unsigned cvt2_fp8(float a, float b, unsigned old) {
#if __has_builtin(__builtin_amdgcn_cvt_pk_fp8_f32)
    return (unsigned)__builtin_amdgcn_cvt_pk_fp8_f32(a, b, (int)old, HI);
#else
    unsigned p = (unsigned)f2e4m3_sw(a) | ((unsigned)f2e4m3_sw(b) << 8);
    return HI ? ((old & 0x0000FFFFu) | (p << 16)) : ((old & 0xFFFF0000u) | p);
#endif
}

static __device__ __forceinline__ float tanh_f(float x) {
    float ex = __expf(2.0f * x);
    return 1.0f - 2.0f * __builtin_amdgcn_rcpf(ex + 1.0f);
}

// ---------------------------------------------------------------------------
// k-permutation (shared by A-storage, B-fragments). K=512 = 4 chunks (s=0..3,
// chunk s produced by col-block W=s). Fragment slot (s, qa=lane>>4, ja=0..31)
// holds global k index:
//   c = 128*s + 64*(ja>>4) + 16*(ja&3) + 4*((ja>>2)&3) + qa        (bijection)
// LDS h-storage byte for (s, qa, ja, row m):
//   addr = s*2048 + qa*512 + (ja>>4)*256 + ((m ^ qa) * 16) + (ja & 15)
// Reads (2x b128 per chunk) and writes (1x b32 per e) are bank-uniform.
// ---------------------------------------------------------------------------

// ---------------------------------------------------------------------------
// Prep 0: W_hx [256,512] f32 -> W_hx^T [512,256] bf16
// ---------------------------------------------------------------------------
__global__ void k_whxT(const float* __restrict__ Whx, unsigned short* __restrict__ WhxT) {
    int idx = blockIdx.x * 256 + threadIdx.x;
    int n = idx >> 8;
    int k = idx & 255;
    WhxT[n * 256 + k] = f2bf(Whx[k * 512 + n]);
}

// ---------------------------------------------------------------------------
// Prep 1: W_hh f32 -> Wf8: fp8 e4m3 B-fragments for mfma 16x16x128 (k-permuted).
// Entry gid = ((Wt*4 + s)*8 + nb)*64 + l holds 32 bytes, byte j:
//   W_hh[c(s, qa=l>>4, j)][col = 128*Wt + 16*nb + (l&15)]
// ---------------------------------------------------------------------------
__global__ void k_wfrag8(const float* __restrict__ Whh, unsigned char* __restrict__ Wf8) {
    int gid = blockIdx.x * 256 + threadIdx.x;    // 8192 entries
    int l = gid & 63, grp = gid >> 6;
    int nb = grp & 7, s = (grp >> 3) & 3, Wt = grp >> 5;
    int col = 128 * Wt + 16 * nb + (l & 15);
    int qa = l >> 4;
    unsigned dw[8];
#pragma unroll
    for (int d = 0; d < 8; ++d) {
        float vv[4];
#pragma unroll
        for (int b = 0; b < 4; ++b) {
            int j = d * 4 + b;
            int c = 128 * s + 64 * (j >> 4) + 16 * (j & 3) + 4 * ((j >> 2) & 3) + qa;
            vv[b] = Whh[(size_t)c * 512 + col];
        }
        unsigned p = cvt2_fp8<false>(vv[0], vv[1], 0u);
        dw[d] = cvt2_fp8<true>(vv[2], vv[3], p);
    }
    u32x8 out;
#pragma unroll
    for (int d = 0; d < 8; ++d) out[d] = dw[d];
    *((u32x8*)Wf8 + gid) = out;
}

// ---------------------------------------------------------------------------
// Phase 1: Z = x @ W_hx + b_h, written in k_rnn's Zr layout:
// Zr block (t,cu,W) = 4096B at ((t*8+cu)*4+W)*4096, [g 0..3][m 0..63][q 0..7] f16,
// value(q) = z[t][16cu + (m>>4)*4 + (q&3)][128W + 16*(2g + (q>>2)) + (m&15)].
// ---------------------------------------------------------------------------
__global__ void __launch_bounds__(256) k_gemm1(const float* __restrict__ x,
                                               const unsigned short* __restrict__ WhxT,
                                               const float* __restrict__ bh,
                                               char* __restrict__ Zr) {
    __shared__ char smem[32768];
    unsigned short* Asm = (unsigned short*)smem;
    unsigned short* Bsm = (unsigned short*)(smem + 8192);

    const int tid = threadIdx.x;
    const int bid = blockIdx.x;
    const int nt = bid & 3, mt = bid >> 2;
    const int r0 = mt * 128, n0 = nt * 128;
    const int w  = tid >> 6, l = tid & 63;
    const int wm = (w >> 1) * 64, wn = (w & 1) * 64;
    const int lr = l & 15, lk = (l >> 4) * 8;

    const int arow = tid >> 2, akc = (tid & 3) * 8;
    const int bcol = tid >> 1, bkc = (tid & 1) * 16;

    f32x4 acc[4][4] = {};

    for (int kk = 0; kk < 256; kk += 32) {
#pragma unroll
        for (int half = 0; half < 2; ++half) {
            const int r = arow + half * 64;
            const float* ap = x + (size_t)(r0 + r) * 256 + kk + akc;
            float4 f0 = *(const float4*)ap;
            float4 f1 = *(const float4*)(ap + 4);
            uint4 av;
            av.x = (unsigned)f2bf(f0.x) | ((unsigned)f2bf(f0.y) << 16);
            av.y = (unsigned)f2bf(f0.z) | ((unsigned)f2bf(f0.w) << 16);
            av.z = (unsigned)f2bf(f1.x) | ((unsigned)f2bf(f1.y) << 16);
            av.w = (unsigned)f2bf(f1.z) | ((unsigned)f2bf(f1.w) << 16);
            *(uint4*)&Asm[r * 32 + akc] = av;
        }
        const unsigned short* bsrc = WhxT + (size_t)(n0 + bcol) * 256 + kk + bkc;
        uint4 bv0 = *(const uint4*)bsrc;
        uint4 bv1 = *(const uint4*)(bsrc + 8);
        *(uint4*)&Bsm[bcol * 32 + bkc] = bv0;
        *(uint4*)&Bsm[bcol * 32 + bkc + 8] = bv1;
        __syncthreads();

        s16x8 af[4], bf[4];
#pragma unroll
        for (int mi = 0; mi < 4; ++mi)
            af[mi] = *(const s16x8*)&Asm[(wm + mi * 16 + lr) * 32 + lk];
#pragma unroll
        for (int ni = 0; ni < 4; ++ni)
            bf[ni] = *(const s16x8*)&Bsm[(wn + ni * 16 + lr) * 32 + lk];
#pragma unroll
        for (int mi = 0; mi < 4; ++mi)
#pragma unroll
            for (int ni = 0; ni < 4; ++ni)
                acc[mi][ni] = __builtin_amdgcn_mfma_f32_16x16x32_bf16(af[mi], bf[ni], acc[mi][ni], 0, 0, 0);
        __syncthreads();
    }

    _Float16* Szr = (_Float16*)smem;   // [cu][g][m][q] = 32 KiB
#pragma unroll
    for (int mi = 0; mi < 4; ++mi)
#pragma unroll
        for (int ni = 0; ni < 4; ++ni) {
            const int col_l = wn + ni * 16 + lr;
            const float bhv = bh[n0 + col_l];
            const int g   = (col_l >> 5) & 3;
            const int qhi = ((col_l >> 4) & 1) * 4;
#pragma unroll
            for (int e = 0; e < 4; ++e) {
                const int b   = wm + mi * 16 + (l >> 4) * 4 + e;
                const int cu  = b >> 4;
                const int m_r = ((b & 15) >> 2) * 16 + lr;
                Szr[((cu * 4 + g) * 64 + m_r) * 8 + qhi + e] = (_Float16)(acc[mi][ni][e] + bhv);
            }
        }
    __syncthreads();
    {
        const uint4* srcv = (const uint4*)smem;
#pragma unroll
        for (int i = 0; i < 8; ++i) {
            const int o   = tid * 128 + i * 16;
            const int cuo = o >> 12;
            char* dst = Zr + ((size_t)((mt * 8 + cuo) * 4 + nt)) * 4096 + (o & 4095);
            *(uint4*)dst = srcv[o >> 4];
        }
    }
}

// ---------------------------------------------------------------------------
// Phase 2: fp8 K=128 MFMA recurrence. 8 WGs x 512 threads (8 waves, 2/SIMD).
// WG cu: batch rows [16cu,16cu+16). Wave (W=w8>>1, hf4=w8&1): cols
// 128W+64hf4 .. +64. B: 4 chunks x 4 nb x 8 regs = 128 AGPR/wave, stationary.
// Per step/wave: 8 ds_read_b128 (A) + 16 v_mfma_f32_16x16x128_f8f6f4 +
// epilogue (tanh->fp8) + 4 ds_write_b32. One barrier/step. z prefetched
// one step ahead with incremental pointers.
// ---------------------------------------------------------------------------
#define MM128(C_, A_, B_) \
    asm("v_mfma_f32_16x16x128_f8f6f4 %0, %1, %2, %0" : "+v"(C_) : "v"(A_), "a"(B_))

__global__
__attribute__((amdgpu_flat_work_group_size(512, 512), amdgpu_waves_per_eu(2, 2)))
void k_rnn(const unsigned char* __restrict__ Wf8,
           const char* __restrict__ Zr,
           float* __restrict__ hf) {
    __shared__ char hA[2][8192];   // h as fp8 A-fragments, double-buffered

    const int tid = threadIdx.x, cu = blockIdx.x;
    const int w8 = tid >> 6;          // wave 0..7
    const int W  = w8 >> 1;           // col block 0..3 (128 cols) == k-chunk it produces
    const int hf4 = w8 & 1;           // nb half
    const int l = tid & 63;
    const int r = l & 15, q = l >> 4;

    // ---- stationary B: 4 chunks x 4 nb tiles x 8 regs -> 128 AGPRs ----
    u32x8 BA[4][4];
    {
        const u32x8* Wb = (const u32x8*)Wf8;
#pragma unroll
        for (int s = 0; s < 4; ++s)
#pragma unroll
            for (int jn = 0; jn < 4; ++jn)
                BA[s][jn] = Wb[(size_t)(((W * 4 + s) * 8) + 4 * hf4 + jn) * 64 + l];
    }

    // h0 = 0 (both buffers): 1024 uint4, 512 threads -> 2 each
    ((uint4*)hA)[tid]       = uint4{0, 0, 0, 0};
    ((uint4*)hA)[512 + tid] = uint4{0, 0, 0, 0};
    __syncthreads();

    // per-thread invariant offsets
    const int qa = r & 3, rq = r >> 2;
    int rdo[4][2];                     // read: [chunk s][half]
#pragma unroll
    for (int s = 0; s < 4; ++s) {
        rdo[s][0] = s * 2048 + q * 512 + ((r ^ q) << 4);
        rdo[s][1] = rdo[s][0] + 256;
    }
    int wd[4];                         // write: [e]
#pragma unroll
    for (int e = 0; e < 4; ++e)
        wd[e] = W * 2048 + qa * 512 + hf4 * 256 + (((4 * q + e) ^ qa) << 4) + 4 * rq;

    // z pointers (incremental; stride per t = 8*4*4096 B)
    const char* zp = Zr + ((size_t)cu * 4 + W) * 4096 + (size_t)(2 * hf4) * 1024 + (size_t)l * 16;
    v8h zl0 = *(const v8h*)zp;
    v8h zl1 = *(const v8h*)(zp + 1024);

    for (int t = 0; t < T_; ++t) {
        char* rb = &hA[t & 1][0];
        char* ob = &hA[(t & 1) ^ 1][0];

        // A fragments: 8 x ds_read_b128 (bank-uniform)
        u32x8 av[4];
#pragma unroll
        for (int s = 0; s < 4; ++s) {
            uint4 lo = *(const uint4*)(rb + rdo[s][0]);
            uint4 hi = *(const uint4*)(rb + rdo[s][1]);
            av[s][0] = lo.x; av[s][1] = lo.y; av[s][2] = lo.z; av[s][3] = lo.w;
            av[s][4] = hi.x; av[s][5] = hi.y; av[s][6] = hi.z; av[s][7] = hi.w;
        }

        // prefetch z for t+1
        const char* zq = (t + 1 < T_) ? zp + 131072 : zp;
        v8h zn0 = *(const v8h*)zq;
        v8h zn1 = *(const v8h*)(zq + 1024);
        zp = zq;

        f32x4 cc[4];
#pragma unroll
        for (int jn = 0; jn < 4; ++jn) cc[jn] = f32x4{0.f, 0.f, 0.f, 0.f};

        // 16 MFMA (K=128), 4 interleaved chains
#pragma unroll
        for (int s = 0; s < 4; ++s)
#pragma unroll
            for (int jn = 0; jn < 4; ++jn)
                MM128(cc[jn], av[s], BA[s][jn]);

        // MFMA -> VALU hazard wall (asm MFMAs opaque to hazard recognizer;
        // K=128 has long latency -> generous wall)
        __builtin_amdgcn_sched_barrier(0);
        asm volatile("s_nop 7\n\ts_nop 7\n\ts_nop 7\n\ts_nop 7\n\ts_nop 7\n\ts_nop 7" ::);
        __builtin_amdgcn_sched_barrier(0);

        // epilogue: z + tanh -> fp8, 4 conflict-free b32 writes
#pragma unroll
        for (int e = 0; e < 4; ++e) {
            float h0 = tanh_f(cc[0][e] + (float)zl0[e]);
            float h1 = tanh_f(cc[1][e] + (float)zl0[4 + e]);
            float h2 = tanh_f(cc[2][e] + (float)zl1[e]);
            float h3 = tanh_f(cc[3][e] + (float)zl1[4 + e]);
            unsigned p = cvt2_fp8<false>(h0, h1, 0u);
            p = cvt2_fp8<true>(h2, h3, p);
            *(unsigned*)(ob + wd[e]) = p;
            if (t == T_ - 1) {
                size_t row = (size_t)(16 * cu + 4 * q + e) * 512 + 128 * W + 64 * hf4 + r;
                hf[row + 0]  = h0; hf[row + 16] = h1;
                hf[row + 32] = h2; hf[row + 48] = h3;
            }
        }
        zl0 = zn0; zl1 = zn1;
        __syncthreads();
    }
}

// ---------------------------------------------------------------------------
// Phase 3: out = h_final @ W_ph + b_p   [128,512]@[512,10]
// ---------------------------------------------------------------------------
__global__ void k_out(const float* __restrict__ hf, const float* __restrict__ Wph,
                      const float* __restrict__ bp, float* __restrict__ out) {
    __shared__ float red[160];
    int b = blockIdx.x, t = threadIdx.x;
    if (t < 160) {
        int c = t >> 4, ks = (t & 15) * 32;
        float s = 0.f;
        for (int u = 0; u < 32; ++u)
            s += hf[b * H_ + ks + u] * Wph[(ks + u) * C_ + c];
        red[t] = s;
    }
    __syncthreads();
    if (t < C_) {
        float s = bp[t];
        for (int i = 0; i < 16; ++i) s += red[t * 16 + i];
        out[b * C_ + t] = s;
    }
}

// ---------------------------------------------------------------------------
extern "C" void kernel_launch(void* const* d_in, const int* in_sizes, int n_in,
                              void* d_out, int out_size, void* d_ws, size_t ws_size,
                              hipStream_t stream) {
    const float* x   = (const float*)d_in[0];   // [512,128,256]
    const float* Whx = (const float*)d_in[1];   // [256,512]
    const float* Whh = (const float*)d_in[2];   // [512,512]
    const float* Wph = (const float*)d_in[3];   // [512,10]
    const float* bh  = (const float*)d_in[4];   // [512]
    const float* bp  = (const float*)d_in[5];   // [10]
    float* out = (float*)d_out;                 // [128,10] f32

    char* ws = (char*)d_ws;
    unsigned short* WhxT = (unsigned short*)(ws);                    // 256 KiB
    unsigned char*  Wf8  = (unsigned char*)(ws + 262144);            // 256 KiB
    char*           Zr   = ws + 786432;                              // 64 MiB
    float*          hf   = (float*)(ws + 786432 + 67108864);         // 256 KiB

    hipLaunchKernelGGL(k_whxT,   dim3(512),  dim3(256), 0, stream, Whx, WhxT);
    hipLaunchKernelGGL(k_wfrag8, dim3(32),   dim3(256), 0, stream, Whh, Wf8);
    hipLaunchKernelGGL(k_gemm1,  dim3(2048), dim3(256), 0, stream, x, WhxT, bh, Zr);
    hipLaunchKernelGGL(k_rnn,    dim3(8),    dim3(512), 0, stream, Wf8, Zr, hf);
    hipLaunchKernelGGL(k_out,    dim3(128),  dim3(256), 0, stream, hf, Wph, bp, out);
}

// Round 13
// 602.753 us; speedup vs baseline: 4.1876x; 1.0949x over previous
//
#include <hip/hip_runtime.h>
#include <cstdint>
#include <cstddef>

#define T_ 512
#define B_ 128
#define D_ 256
#define H_ 512
#define C_ 10

typedef float  f32x4 __attribute__((ext_vector_type(4)));
typedef short  s16x8 __attribute__((ext_vector_type(8)));
typedef _Float16 v8h  __attribute__((ext_vector_type(8)));
typedef unsigned u32x8 __attribute__((ext_vector_type(8)));

static __device__ __forceinline__ unsigned short f2bf(float f) {
    unsigned u = __builtin_bit_cast(unsigned, f);
    unsigned r = u + 0x7FFFu + ((u >> 16) & 1u);
    return (unsigned short)(r >> 16);
}

// ---- fp8 e4m3fn encode (HW cvt if available, else software RNE) ----
static __device__ __forceinline__ unsigned char f2e4m3_sw(float f) {
    unsigned u = __builtin_bit_cast(unsigned, f);
    unsigned sgn = (u >> 24) & 0x80u;
    float a = fabsf(f);
    if (a != a) return (unsigned char)(sgn | 0x7E);
    if (a >= 448.0f) return (unsigned char)(sgn | 0x7E);
    if (a < 0.015625f) {
        int qv = (int)rintf(a * 512.0f);
        if (qv > 7) return (unsigned char)(sgn | 0x08);
        return (unsigned char)(sgn | qv);
    }
    unsigned ub = __builtin_bit_cast(unsigned, a);
    unsigned rr = ub + 0x7FFFFu + ((ub >> 20) & 1u);
    int E = (int)(rr >> 23) - 127 + 7;
    unsigned m = (rr >> 20) & 7u;
    if (E < 1)  { E = 0; m = 7; }
    if (E > 15) { E = 15; m = 6; }
    if (E == 15 && m == 7) m = 6;
    return (unsigned char)(sgn | ((unsigned)E << 3) | m);
}
template <bool HI>
static __device__ __forceinline__ unsigned cvt2_fp8(float a, float b, unsigned old) {
#if __has_builtin(__builtin_amdgcn_cvt_pk_fp8_f32)
    return (unsigned)__builtin_amdgcn_cvt_pk_fp8_f32(a, b, (int)old, HI);
#else
    unsigned p = (unsigned)f2e4m3_sw(a) | ((unsigned)f2e4m3_sw(b) << 8);
    return HI ? ((old & 0x0000FFFFu) | (p << 16)) : ((old & 0xFFFF0000u) | p);
#endif
}

static __device__ __forceinline__ float tanh_f(float x) {
    float ex = __expf(2.0f * x);
    return 1.0f - 2.0f * __builtin_amdgcn_rcpf(ex + 1.0f);
}

// ---------------------------------------------------------------------------
// k-permutation (shared by A-storage, B-fragments). K=512 = 4 chunks (s=0..3,
// chunk s produced by col-block W=s). Fragment slot (s, qa=lane>>4, ja=0..31)
// holds global k index:
//   c = 128*s + 64*(ja>>4) + 16*(ja&3) + 4*((ja>>2)&3) + qa        (bijection)
// LDS h-storage byte for (s, qa, ja, row m):
//   addr = s*2048 + qa*512 + (ja>>4)*256 + ((m ^ qa) * 16) + (ja & 15)
// ---------------------------------------------------------------------------

// ---------------------------------------------------------------------------
// Prep 0: W_hx [256,512] f32 -> W_hx^T [512,256] bf16
// ---------------------------------------------------------------------------
__global__ void k_whxT(const float* __restrict__ Whx, unsigned short* __restrict__ WhxT) {
    int idx = blockIdx.x * 256 + threadIdx.x;
    int n = idx >> 8;
    int k = idx & 255;
    WhxT[n * 256 + k] = f2bf(Whx[k * 512 + n]);
}

// ---------------------------------------------------------------------------
// Prep 1: W_hh f32 -> Wf8: fp8 e4m3 B-fragments for mfma 16x16x128 (k-permuted).
// ---------------------------------------------------------------------------
__global__ void k_wfrag8(const float* __restrict__ Whh, unsigned char* __restrict__ Wf8) {
    int gid = blockIdx.x * 256 + threadIdx.x;    // 8192 entries
    int l = gid & 63, grp = gid >> 6;
    int nb = grp & 7, s = (grp >> 3) & 3, Wt = grp >> 5;
    int col = 128 * Wt + 16 * nb + (l & 15);
    int qa = l >> 4;
    unsigned dw[8];
#pragma unroll
    for (int d = 0; d < 8; ++d) {
        float vv[4];
#pragma unroll
        for (int b = 0; b < 4; ++b) {
            int j = d * 4 + b;
            int c = 128 * s + 64 * (j >> 4) + 16 * (j & 3) + 4 * ((j >> 2) & 3) + qa;
            vv[b] = Whh[(size_t)c * 512 + col];
        }
        unsigned p = cvt2_fp8<false>(vv[0], vv[1], 0u);
        dw[d] = cvt2_fp8<true>(vv[2], vv[3], p);
    }
    u32x8 out;
#pragma unroll
    for (int d = 0; d < 8; ++d) out[d] = dw[d];
    *((u32x8*)Wf8 + gid) = out;
}

// ---------------------------------------------------------------------------
// Phase 1: Z = x @ W_hx + b_h, written in k_rnn's Zr layout.
// ---------------------------------------------------------------------------
__global__ void __launch_bounds__(256) k_gemm1(const float* __restrict__ x,
                                               const unsigned short* __restrict__ WhxT,
                                               const float* __restrict__ bh,
                                               char* __restrict__ Zr) {
    __shared__ char smem[32768];
    unsigned short* Asm = (unsigned short*)smem;
    unsigned short* Bsm = (unsigned short*)(smem + 8192);

    const int tid = threadIdx.x;
    const int bid = blockIdx.x;
    const int nt = bid & 3, mt = bid >> 2;
    const int r0 = mt * 128, n0 = nt * 128;
    const int w  = tid >> 6, l = tid & 63;
    const int wm = (w >> 1) * 64, wn = (w & 1) * 64;
    const int lr = l & 15, lk = (l >> 4) * 8;

    const int arow = tid >> 2, akc = (tid & 3) * 8;
    const int bcol = tid >> 1, bkc = (tid & 1) * 16;

    f32x4 acc[4][4] = {};

    for (int kk = 0; kk < 256; kk += 32) {
#pragma unroll
        for (int half = 0; half < 2; ++half) {
            const int r = arow + half * 64;
            const float* ap = x + (size_t)(r0 + r) * 256 + kk + akc;
            float4 f0 = *(const float4*)ap;
            float4 f1 = *(const float4*)(ap + 4);
            uint4 av;
            av.x = (unsigned)f2bf(f0.x) | ((unsigned)f2bf(f0.y) << 16);
            av.y = (unsigned)f2bf(f0.z) | ((unsigned)f2bf(f0.w) << 16);
            av.z = (unsigned)f2bf(f1.x) | ((unsigned)f2bf(f1.y) << 16);
            av.w = (unsigned)f2bf(f1.z) | ((unsigned)f2bf(f1.w) << 16);
            *(uint4*)&Asm[r * 32 + akc] = av;
        }
        const unsigned short* bsrc = WhxT + (size_t)(n0 + bcol) * 256 + kk + bkc;
        uint4 bv0 = *(const uint4*)bsrc;
        uint4 bv1 = *(const uint4*)(bsrc + 8);
        *(uint4*)&Bsm[bcol * 32 + bkc] = bv0;
        *(uint4*)&Bsm[bcol * 32 + bkc + 8] = bv1;
        __syncthreads();

        s16x8 af[4], bf[4];
#pragma unroll
        for (int mi = 0; mi < 4; ++mi)
            af[mi] = *(const s16x8*)&Asm[(wm + mi * 16 + lr) * 32 + lk];
#pragma unroll
        for (int ni = 0; ni < 4; ++ni)
            bf[ni] = *(const s16x8*)&Bsm[(wn + ni * 16 + lr) * 32 + lk];
#pragma unroll
        for (int mi = 0; mi < 4; ++mi)
#pragma unroll
            for (int ni = 0; ni < 4; ++ni)
                acc[mi][ni] = __builtin_amdgcn_mfma_f32_16x16x32_bf16(af[mi], bf[ni], acc[mi][ni], 0, 0, 0);
        __syncthreads();
    }

    _Float16* Szr = (_Float16*)smem;   // [cu][g][m][q] = 32 KiB
#pragma unroll
    for (int mi = 0; mi < 4; ++mi)
#pragma unroll
        for (int ni = 0; ni < 4; ++ni) {
            const int col_l = wn + ni * 16 + lr;
            const float bhv = bh[n0 + col_l];
            const int g   = (col_l >> 5) & 3;
            const int qhi = ((col_l >> 4) & 1) * 4;
#pragma unroll
            for (int e = 0; e < 4; ++e) {
                const int b   = wm + mi * 16 + (l >> 4) * 4 + e;
                const int cu  = b >> 4;
                const int m_r = ((b & 15) >> 2) * 16 + lr;
                Szr[((cu * 4 + g) * 64 + m_r) * 8 + qhi + e] = (_Float16)(acc[mi][ni][e] + bhv);
            }
        }
    __syncthreads();
    {
        const uint4* srcv = (const uint4*)smem;
#pragma unroll
        for (int i = 0; i < 8; ++i) {
            const int o   = tid * 128 + i * 16;
            const int cuo = o >> 12;
            char* dst = Zr + ((size_t)((mt * 8 + cuo) * 4 + nt)) * 4096 + (o & 4095);
            *(uint4*)dst = srcv[o >> 4];
        }
    }
}

// ---------------------------------------------------------------------------
// Phase 2: fp8 K=128 MFMA recurrence, pair-pipelined. 8 WGs x 512 threads
// (8 waves, 2/SIMD). Step = [MFMA cc0,cc1 | wall | epilogue0] then
// [MFMA cc2,cc3 | wall | epilogue1] -- epilogue VALU of one pair overlaps the
// other pair's / other wave's MFMAs in the matrix pipe. C is initialized
// from z (no zero-init, no late add). Writes: 2x ds_write_b16 per e.
// ---------------------------------------------------------------------------
#define MM128(C_, A_, B_) \
    asm("v_mfma_f32_16x16x128_f8f6f4 %0, %1, %2, %0" : "+v"(C_) : "v"(A_), "a"(B_))

__global__
__attribute__((amdgpu_flat_work_group_size(512, 512), amdgpu_waves_per_eu(2, 2)))
void k_rnn(const unsigned char* __restrict__ Wf8,
           const char* __restrict__ Zr,
           float* __restrict__ hf) {
    __shared__ char hA[2][8192];   // h as fp8 A-fragments, double-buffered

    const int tid = threadIdx.x, cu = blockIdx.x;
    const int w8 = tid >> 6;          // wave 0..7
    const int W  = w8 >> 1;           // col block 0..3 == k-chunk it produces
    const int hf4 = w8 & 1;           // nb half
    const int l = tid & 63;
    const int r = l & 15, q = l >> 4;

    // ---- stationary B: 4 chunks x 4 nb tiles x 8 regs -> 128 AGPRs ----
    u32x8 BA[4][4];
    {
        const u32x8* Wb = (const u32x8*)Wf8;
#pragma unroll
        for (int s = 0; s < 4; ++s)
#pragma unroll
            for (int jn = 0; jn < 4; ++jn)
                BA[s][jn] = Wb[(size_t)(((W * 4 + s) * 8) + 4 * hf4 + jn) * 64 + l];
    }

    // h0 = 0 (both buffers)
    ((uint4*)hA)[tid]       = uint4{0, 0, 0, 0};
    ((uint4*)hA)[512 + tid] = uint4{0, 0, 0, 0};
    __syncthreads();

    // per-thread invariant offsets
    const int qa = r & 3, rq = r >> 2;
    int rdo[4][2];                     // read: [chunk s][half]
#pragma unroll
    for (int s = 0; s < 4; ++s) {
        rdo[s][0] = s * 2048 + q * 512 + ((r ^ q) << 4);
        rdo[s][1] = rdo[s][0] + 256;
    }
    int wd[4];                         // write: [e] (bytes jn0,1 at +0; jn2,3 at +2)
#pragma unroll
    for (int e = 0; e < 4; ++e)
        wd[e] = W * 2048 + qa * 512 + hf4 * 256 + (((4 * q + e) ^ qa) << 4) + 4 * rq;

    // z pointers (incremental; stride per t = 8*4*4096 B)
    const char* zp = Zr + ((size_t)cu * 4 + W) * 4096 + (size_t)(2 * hf4) * 1024 + (size_t)l * 16;
    v8h zl0 = *(const v8h*)zp;
    v8h zl1 = *(const v8h*)(zp + 1024);

    for (int t = 0; t < T_; ++t) {
        char* rb = &hA[t & 1][0];
        char* ob = &hA[(t & 1) ^ 1][0];

        // A fragments: 8 x ds_read_b128 (bank-uniform)
        u32x8 av[4];
#pragma unroll
        for (int s = 0; s < 4; ++s) {
            uint4 lo = *(const uint4*)(rb + rdo[s][0]);
            uint4 hi = *(const uint4*)(rb + rdo[s][1]);
            av[s][0] = lo.x; av[s][1] = lo.y; av[s][2] = lo.z; av[s][3] = lo.w;
            av[s][4] = hi.x; av[s][5] = hi.y; av[s][6] = hi.z; av[s][7] = hi.w;
        }

        // prefetch z for t+1
        const char* zq = (t + 1 < T_) ? zp + 131072 : zp;
        v8h zn0 = *(const v8h*)zq;
        v8h zn1 = *(const v8h*)(zq + 1024);
        zp = zq;

        // ================= pair 0: jn = 0,1 (z-initialized C) =================
        f32x4 cc0, cc1;
#pragma unroll
        for (int e = 0; e < 4; ++e) {
            cc0[e] = (float)zl0[e];
            cc1[e] = (float)zl0[4 + e];
        }
#pragma unroll
        for (int s = 0; s < 4; ++s) {
            MM128(cc0, av[s], BA[s][0]);
            MM128(cc1, av[s], BA[s][1]);
        }
        __builtin_amdgcn_sched_barrier(0);
        asm volatile("s_nop 7\n\ts_nop 7\n\ts_nop 7\n\ts_nop 7\n\ts_nop 7\n\ts_nop 7" ::);
        __builtin_amdgcn_sched_barrier(0);
#pragma unroll
        for (int e = 0; e < 4; ++e) {
            float h0 = tanh_f(cc0[e]);
            float h1 = tanh_f(cc1[e]);
            unsigned p = cvt2_fp8<false>(h0, h1, 0u);
            *(unsigned short*)(ob + wd[e]) = (unsigned short)p;
            if (t == T_ - 1) {
                size_t row = (size_t)(16 * cu + 4 * q + e) * 512 + 128 * W + 64 * hf4 + r;
                hf[row + 0]  = h0; hf[row + 16] = h1;
            }
        }

        // ================= pair 1: jn = 2,3 =================
        f32x4 cc2, cc3;
#pragma unroll
        for (int e = 0; e < 4; ++e) {
            cc2[e] = (float)zl1[e];
            cc3[e] = (float)zl1[4 + e];
        }
#pragma unroll
        for (int s = 0; s < 4; ++s) {
            MM128(cc2, av[s], BA[s][2]);
            MM128(cc3, av[s], BA[s][3]);
        }
        __builtin_amdgcn_sched_barrier(0);
        asm volatile("s_nop 7\n\ts_nop 7\n\ts_nop 7\n\ts_nop 7\n\ts_nop 7\n\ts_nop 7" ::);
        __builtin_amdgcn_sched_barrier(0);
#pragma unroll
        for (int e = 0; e < 4; ++e) {
            float h2 = tanh_f(cc2[e]);
            float h3 = tanh_f(cc3[e]);
            unsigned p = cvt2_fp8<false>(h2, h3, 0u);
            *(unsigned short*)(ob + wd[e] + 2) = (unsigned short)p;
            if (t == T_ - 1) {
                size_t row = (size_t)(16 * cu + 4 * q + e) * 512 + 128 * W + 64 * hf4 + r;
                hf[row + 32] = h2; hf[row + 48] = h3;
            }
        }

        zl0 = zn0; zl1 = zn1;
        __syncthreads();
    }
}

// ---------------------------------------------------------------------------
// Phase 3: out = h_final @ W_ph + b_p   [128,512]@[512,10]
// ---------------------------------------------------------------------------
__global__ void k_out(const float* __restrict__ hf, const float* __restrict__ Wph,
                      const float* __restrict__ bp, float* __restrict__ out) {
    __shared__ float red[160];
    int b = blockIdx.x, t = threadIdx.x;
    if (t < 160) {
        int c = t >> 4, ks = (t & 15) * 32;
        float s = 0.f;
        for (int u = 0; u < 32; ++u)
            s += hf[b * H_ + ks + u] * Wph[(ks + u) * C_ + c];
        red[t] = s;
    }
    __syncthreads();
    if (t < C_) {
        float s = bp[t];
        for (int i = 0; i < 16; ++i) s += red[t * 16 + i];
        out[b * C_ + t] = s;
    }
}

// ---------------------------------------------------------------------------
extern "C" void kernel_launch(void* const* d_in, const int* in_sizes, int n_in,
                              void* d_out, int out_size, void* d_ws, size_t ws_size,
                              hipStream_t stream) {
    const float* x   = (const float*)d_in[0];   // [512,128,256]
    const float* Whx = (const float*)d_in[1];   // [256,512]
    const float* Whh = (const float*)d_in[2];   // [512,512]
    const float* Wph = (const float*)d_in[3];   // [512,10]
    const float* bh  = (const float*)d_in[4];   // [512]
    const float* bp  = (const float*)d_in[5];   // [10]
    float* out = (float*)d_out;                 // [128,10] f32

    char* ws = (char*)d_ws;
    unsigned short* WhxT = (unsigned short*)(ws);                    // 256 KiB
    unsigned char*  Wf8  = (unsigned char*)(ws + 262144);            // 256 KiB
    char*           Zr   = ws + 786432;                              // 64 MiB
    float*          hf   = (float*)(ws + 786432 + 67108864);         // 256 KiB

    hipLaunchKernelGGL(k_whxT,   dim3(512),  dim3(256), 0, stream, Whx, WhxT);
    hipLaunchKernelGGL(k_wfrag8, dim3(32),   dim3(256), 0, stream, Whh, Wf8);
    hipLaunchKernelGGL(k_gemm1,  dim3(2048), dim3(256), 0, stream, x, WhxT, bh, Zr);
    hipLaunchKernelGGL(k_rnn,    dim3(8),    dim3(512), 0, stream, Wf8, Zr, hf);
    hipLaunchKernelGGL(k_out,    dim3(128),  dim3(256), 0, stream, hf, Wph, bp, out);
}